// Round 12
// baseline (412.536 us; speedup 1.0000x reference)
//
#include <hip/hip_runtime.h>
#include <cstddef>

#define D256 256

typedef __attribute__((ext_vector_type(8))) short bf16x8;
typedef __attribute__((ext_vector_type(4))) float f32x4;

// global -> LDS direct (16B per lane, wave-uniform LDS base + lane*16)
#define GLOAD16(gptr, lptr)                                                         \
    __builtin_amdgcn_global_load_lds(                                               \
        (const __attribute__((address_space(1))) unsigned int*)(gptr),              \
        (__attribute__((address_space(3))) unsigned int*)(lptr), 16, 0, 0)

__device__ __forceinline__ ushort f2bf(float f) {
    unsigned u = __float_as_uint(f);
    return (ushort)((u + 0x7FFFu + ((u >> 16) & 1u)) >> 16);   // RNE
}
__device__ __forceinline__ ushort umax16(ushort a, ushort b) { return a > b ? a : b; }
__device__ __forceinline__ ushort4 vmax4(ushort4 a, ushort4 b) {
    return make_ushort4(umax16(a.x, b.x), umax16(a.y, b.y),
                        umax16(a.z, b.z), umax16(a.w, b.w));
}

// ---------------- MFMA GEMM: out = act( A@Bt^T (+ A2@Bt2^T) + bias ) ----------------
// A [M,256] bf16 row-major; Bt [256,256] bf16 = W^T (row n = output col, K-contiguous).
// 128x128 tile, 4 waves (2x2), 64x64/wave, BK=32, 16x16x32 MFMA.
// A/A2 staged via global_load_lds (2-phase dbuf). B/B2 fragments loaded DIRECTLY
// from global into registers each K-step (weights are L2-resident; skipping LDS
// halves the ds_read critical path: 8x12=96 cyc < 32 MFMA = 155 cyc -> MFMA-bound).
// Swapped-operand mfma(bf, af): D frag = (m = lane&15, n = kg*4 + reg)
// -> float4/ushort4 epilogue stores.
template<int DUAL, int RELU, int OUT_BF16>
__global__ __launch_bounds__(256)
void mfma_gemm_kernel(const ushort* __restrict__ A, const ushort* __restrict__ Bt,
                      const ushort* __restrict__ A2, const ushort* __restrict__ Bt2,
                      const float* __restrict__ bias, void* __restrict__ outp, int M)
{
    constexpr int TILES = DUAL ? 2 : 1;          // A[,A2] only — B bypasses LDS
    constexpr int BUFSZ = TILES * 4096;          // ushorts per buffer
    __shared__ ushort smem[2 * BUFSZ];

    const int t    = threadIdx.x;
    const int m0   = blockIdx.x * 128;
    const int n0   = blockIdx.y * 128;
    const int lane = t & 63;
    const int wave = t >> 6;
    const int wr   = (wave >> 1) * 64;   // wave row base in tile
    const int wc   = (wave & 1) * 64;    // wave col base in tile
    const int lr   = lane & 15;
    const int kg   = lane >> 4;          // k-group 0..3

    // staging: wave stages rows [wave*32, wave*32+32) of each A tile, 2 insts x 16 rows
    const int lrow  = lane >> 2;         // row within a 16-row instruction
    const int lch   = lane & 3;          // 16B chunk within the 64B row
    const int srow0 = wave * 32;

    f32x4 acc[4][4];
#pragma unroll
    for (int i = 0; i < 4; ++i)
#pragma unroll
        for (int j = 0; j < 4; ++j) acc[i][j] = (f32x4)(0.0f);

    // per-lane global base addresses for the B fragments (row = output col)
    const ushort* Brow[4];
    const ushort* B2row[4];
#pragma unroll
    for (int ni = 0; ni < 4; ++ni) {
        Brow[ni]  = Bt + (size_t)(n0 + wc + ni * 16 + lr) * D256 + kg * 8;
        B2row[ni] = DUAL ? (Bt2 + (size_t)(n0 + wc + ni * 16 + lr) * D256 + kg * 8)
                         : nullptr;
    }

    // issue the A staging loads for K-step k0 into buffer `buf`
    auto STAGE = [&](int buf, int k0) {
        ushort* const base = smem + buf * BUFSZ;
#pragma unroll
        for (int i = 0; i < 2; ++i) {
            const int r   = srow0 + i * 16;
            const int ar  = m0 + r + lrow;
            const int arc = ar < M ? ar : (M - 1);          // clamp tail rows
            const size_t ga = (size_t)arc * D256 + k0 + lch * 8;
            GLOAD16(A + ga, base + r * 32);
            if (DUAL) GLOAD16(A2 + ga, base + 4096 + r * 32);
        }
    };

    STAGE(0, 0);                                  // prologue prefetch
#pragma unroll
    for (int ks = 0; ks < 8; ++ks) {              // 8 K-steps of 32
        const int cur = ks & 1;
        const int k0  = ks * 32;
        __syncthreads();   // drains vmcnt(0): buf[cur] ready; prev reads of buf[cur^1] done
        if (ks < 7) STAGE(cur ^ 1, k0 + 32);      // overlap with MFMA below

        // B fragments straight from global (L2-hot weights)
        bf16x8 bf[4], bf2[4];
#pragma unroll
        for (int ni = 0; ni < 4; ++ni) bf[ni] = *(const bf16x8*)(Brow[ni] + k0);
        if (DUAL) {
#pragma unroll
            for (int ni = 0; ni < 4; ++ni) bf2[ni] = *(const bf16x8*)(B2row[ni] + k0);
        }

        ushort* const base = smem + cur * BUFSZ;
        bf16x8 af[4];
#pragma unroll
        for (int mi = 0; mi < 4; ++mi)
            af[mi] = *(const bf16x8*)&base[(wr + mi * 16 + lr) * 32 + kg * 8];
#pragma unroll
        for (int mi = 0; mi < 4; ++mi)
#pragma unroll
            for (int ni = 0; ni < 4; ++ni)
                acc[mi][ni] = __builtin_amdgcn_mfma_f32_16x16x32_bf16(
                    bf[ni], af[mi], acc[mi][ni], 0, 0, 0);   // swapped operands
        if (DUAL) {
            bf16x8 af2[4];
#pragma unroll
            for (int mi = 0; mi < 4; ++mi)
                af2[mi] = *(const bf16x8*)&base[4096 + (wr + mi * 16 + lr) * 32 + kg * 8];
#pragma unroll
            for (int mi = 0; mi < 4; ++mi)
#pragma unroll
                for (int ni = 0; ni < 4; ++ni)
                    acc[mi][ni] = __builtin_amdgcn_mfma_f32_16x16x32_bf16(
                        bf2[ni], af2[mi], acc[mi][ni], 0, 0, 0);
        }
    }

    // Swapped C/D layout: m = lane&15, n = kg*4 + reg  -> vector stores
#pragma unroll
    for (int ni = 0; ni < 4; ++ni) {
        const int colb = n0 + wc + ni * 16 + kg * 4;
        const float4 bb = *(const float4*)(bias + colb);
#pragma unroll
        for (int mi = 0; mi < 4; ++mi) {
            const int row = m0 + wr + mi * 16 + lr;
            if (row < M) {
                const f32x4 a = acc[mi][ni];
                float4 o;
                o.x = a[0] + bb.x;
                o.y = a[1] + bb.y;
                o.z = a[2] + bb.z;
                o.w = a[3] + bb.w;
                if (RELU) {
                    o.x = fmaxf(o.x, 0.f); o.y = fmaxf(o.y, 0.f);
                    o.z = fmaxf(o.z, 0.f); o.w = fmaxf(o.w, 0.f);
                }
                if (OUT_BF16) {
                    ushort4 ob;
                    ob.x = f2bf(o.x); ob.y = f2bf(o.y);
                    ob.z = f2bf(o.z); ob.w = f2bf(o.w);
                    *(ushort4*)((ushort*)outp + (size_t)row * D256 + colb) = ob;
                } else {
                    *(float4*)((float*)outp + (size_t)row * D256 + colb) = o;
                }
            }
        }
    }
}

// ---------------- fp32 -> bf16 convert ----------------
__global__ __launch_bounds__(256)
void f2bf_kernel(const float* __restrict__ in, ushort* __restrict__ out, int n4)
{
    const int i = blockIdx.x * 256 + threadIdx.x;
    if (i >= n4) return;
    const float4 v = ((const float4*)in)[i];
    ushort4 o;
    o.x = f2bf(v.x); o.y = f2bf(v.y); o.z = f2bf(v.z); o.w = f2bf(v.w);
    ((ushort4*)out)[i] = o;
}

// ---------------- weight transpose+convert: Bt[n][k] = bf16(W[k][n]) ----------------
struct WP  { const float* w; ushort* o; };
struct WP6 { WP p[6]; };
__global__ __launch_bounds__(256)
void wtrans_kernel(WP6 ps)
{
    const float* __restrict__ W = ps.p[blockIdx.z].w;
    ushort* __restrict__ O      = ps.p[blockIdx.z].o;
    __shared__ float sm[32][33];
    const int tx = threadIdx.x & 31, ty = threadIdx.x >> 5;
    const int k0 = blockIdx.x * 32, n0 = blockIdx.y * 32;
#pragma unroll
    for (int i = 0; i < 4; ++i)
        sm[ty + i * 8][tx] = W[(size_t)(k0 + ty + i * 8) * D256 + n0 + tx];
    __syncthreads();
#pragma unroll
    for (int i = 0; i < 4; ++i)
        O[(size_t)(n0 + ty + i * 8) * D256 + k0 + tx] = f2bf(sm[tx][ty + i * 8]);
}

// ---------------- CSR build: histogram -> hierarchical scan -> bucket scatter ----------------
// int4-vectorized edge reads (4 edges/thread); atomic count unchanged.
__global__ __launch_bounds__(256)
void hist_kernel(const int* __restrict__ dst, int* __restrict__ deg, int E)
{
    const int nq = E >> 2;
    const int i  = blockIdx.x * 256 + threadIdx.x;
    if (i < nq) {
        const int4 d = ((const int4*)dst)[i];
        atomicAdd(&deg[d.x], 1);
        atomicAdd(&deg[d.y], 1);
        atomicAdd(&deg[d.z], 1);
        atomicAdd(&deg[d.w], 1);
    } else if (i == nq) {
        for (int e = nq * 4; e < E; ++e) atomicAdd(&deg[dst[e]], 1);
    }
}

// per-block (1024 elems) inclusive scan: wave shfl scan + 16-wave LDS combine
__global__ __launch_bounds__(1024)
void blockscan_kernel(const int* __restrict__ deg, int* __restrict__ incl,
                      int* __restrict__ partials, int N)
{
    __shared__ int wt[16];
    const int i    = blockIdx.x * 1024 + threadIdx.x;
    const int lane = threadIdx.x & 63;
    const int wv   = threadIdx.x >> 6;
    const int v    = (i < N) ? deg[i] : 0;
    int s = v;
#pragma unroll
    for (int o = 1; o < 64; o <<= 1) {
        const int t = __shfl_up(s, o);
        if (lane >= o) s += t;
    }
    if (lane == 63) wt[wv] = s;
    __syncthreads();
    if (wv == 0 && lane < 16) {
        const int w = wt[lane];
        int ws = w;
#pragma unroll
        for (int o = 1; o < 16; o <<= 1) {
            const int t = __shfl_up(ws, o);
            if (lane >= o) ws += t;
        }
        wt[lane] = ws - w;   // exclusive wave offset
    }
    __syncthreads();
    s += wt[wv];
    if (i < N) incl[i] = s;
    if (threadIdx.x == 1023) partials[blockIdx.x] = s;
}

// scan the (<=1024) block totals into exclusive offsets; single block
__global__ __launch_bounds__(1024)
void scanp_kernel(int* __restrict__ partials, int nb)
{
    __shared__ int sm[1024];
    const int v = (threadIdx.x < (unsigned)nb) ? partials[threadIdx.x] : 0;
    sm[threadIdx.x] = v;
    __syncthreads();
#pragma unroll
    for (int off = 1; off < 1024; off <<= 1) {
        const int t = (threadIdx.x >= (unsigned)off) ? sm[threadIdx.x - off] : 0;
        __syncthreads();
        sm[threadIdx.x] += t;
        __syncthreads();
    }
    if (threadIdx.x < (unsigned)nb) partials[threadIdx.x] = sm[threadIdx.x] - v;
}

__global__ __launch_bounds__(1024)
void finalize_kernel(const int* __restrict__ deg, const int* __restrict__ incl,
                     const int* __restrict__ partials, int* __restrict__ row_ptr,
                     int* __restrict__ cursor, int N, int E)
{
    const int i = blockIdx.x * 1024 + threadIdx.x;
    if (i < N) {
        const int ex = partials[blockIdx.x] + incl[i] - deg[i];
        row_ptr[i] = ex;
        cursor[i]  = ex;
    }
    if (i == 0) row_ptr[N] = E;
}

__global__ __launch_bounds__(256)
void bucket_kernel(const int* __restrict__ src, const int* __restrict__ dst,
                   int* __restrict__ cursor, int* __restrict__ esrc, int E)
{
    const int nq = E >> 2;
    const int i  = blockIdx.x * 256 + threadIdx.x;
    if (i < nq) {
        const int4 d = ((const int4*)dst)[i];
        const int4 s = ((const int4*)src)[i];
        esrc[atomicAdd(&cursor[d.x], 1)] = s.x;
        esrc[atomicAdd(&cursor[d.y], 1)] = s.y;
        esrc[atomicAdd(&cursor[d.z], 1)] = s.z;
        esrc[atomicAdd(&cursor[d.w], 1)] = s.w;
    } else if (i == nq) {
        for (int e = nq * 4; e < E; ++e)
            esrc[atomicAdd(&cursor[dst[e]], 1)] = src[e];
    }
}

// ---------------- node-parallel segment max over bf16 rows ----------------
// m >= 0 (relu), so unsigned-short compare == float compare; 0 = identity.
// Wave-per-node: 64 lanes read one full 512B row coalesced.
__global__ __launch_bounds__(256)
void agg_max_kernel(const int* __restrict__ row_ptr, const int* __restrict__ esrc,
                    const ushort* __restrict__ m, ushort* __restrict__ agg, int N)
{
    const int wid  = (int)(((size_t)blockIdx.x * 256 + threadIdx.x) >> 6);
    const int lane = threadIdx.x & 63;
    if (wid >= N) return;
    const int beg = row_ptr[wid];
    const int end = row_ptr[wid + 1];
    const size_t off = (size_t)(lane * 4);

    ushort4 a0 = make_ushort4(0, 0, 0, 0);
    ushort4 a1 = a0, a2 = a0, a3 = a0;
    int e = beg;
    for (; e + 8 <= end; e += 8) {
        int s[8];
#pragma unroll
        for (int q = 0; q < 8; ++q) s[q] = esrc[e + q];
        ushort4 v[8];
#pragma unroll
        for (int q = 0; q < 8; ++q)
            v[q] = *(const ushort4*)(m + (size_t)s[q] * D256 + off);
        a0 = vmax4(a0, vmax4(v[0], v[4]));
        a1 = vmax4(a1, vmax4(v[1], v[5]));
        a2 = vmax4(a2, vmax4(v[2], v[6]));
        a3 = vmax4(a3, vmax4(v[3], v[7]));
    }
    for (; e + 2 <= end; e += 2) {
        const int s0 = esrc[e];
        const int s1 = esrc[e + 1];
        const ushort4 v0 = *(const ushort4*)(m + (size_t)s0 * D256 + off);
        const ushort4 v1 = *(const ushort4*)(m + (size_t)s1 * D256 + off);
        a0 = vmax4(a0, v0);
        a1 = vmax4(a1, v1);
    }
    if (e < end) {
        const ushort4 v0 = *(const ushort4*)(m + (size_t)esrc[e] * D256 + off);
        a2 = vmax4(a2, v0);
    }
    const ushort4 r = vmax4(vmax4(a0, a1), vmax4(a2, a3));
    *(ushort4*)(agg + (size_t)wid * D256 + off) = r;
}

// ------------- row-wise L2 normalize: fp32 out + bf16 copy -------------
__global__ __launch_bounds__(256)
void l2norm_kernel(const float* __restrict__ in, float* __restrict__ out_f,
                   ushort* __restrict__ out_b, int M)
{
    const int wid  = (int)(((size_t)blockIdx.x * 256 + threadIdx.x) >> 6);
    const int lane = threadIdx.x & 63;
    if (wid >= M) return;
    const float4 v = *(const float4*)(in + (size_t)wid * D256 + lane * 4);
    float ss = v.x * v.x + v.y * v.y + v.z * v.z + v.w * v.w;
#pragma unroll
    for (int o = 32; o >= 1; o >>= 1) ss += __shfl_xor(ss, o);
    const float inv = 1.0f / fmaxf(sqrtf(ss), 1e-12f);
    float4 o4;
    o4.x = v.x * inv; o4.y = v.y * inv; o4.z = v.z * inv; o4.w = v.w * inv;
    *(float4*)(out_f + (size_t)wid * D256 + lane * 4) = o4;
    ushort4 ob;
    ob.x = f2bf(o4.x); ob.y = f2bf(o4.y); ob.z = f2bf(o4.z); ob.w = f2bf(o4.w);
    *(ushort4*)(out_b + (size_t)wid * D256 + lane * 4) = ob;
}

extern "C" void kernel_launch(void* const* d_in, const int* in_sizes, int n_in,
                              void* d_out, int out_size, void* d_ws, size_t ws_size,
                              hipStream_t stream)
{
    const float* x        = (const float*)d_in[0];
    const int*   src      = (const int*)  d_in[1];
    const int*   dst      = (const int*)  d_in[2];
    const float* W_pool0  = (const float*)d_in[3];
    const float* b_pool0  = (const float*)d_in[4];
    const float* W_self0  = (const float*)d_in[5];
    const float* W_neigh0 = (const float*)d_in[6];
    const float* b0       = (const float*)d_in[7];
    const float* W_pool1  = (const float*)d_in[8];
    const float* b_pool1  = (const float*)d_in[9];
    const float* W_self1  = (const float*)d_in[10];
    const float* W_neigh1 = (const float*)d_in[11];
    const float* b1       = (const float*)d_in[12];

    const int N = in_sizes[0] / D256;
    const int E = in_sizes[1];
    const size_t NR = (size_t)N * D256;   // elems per node matrix

    float* h1  = (float*)d_out;                     // [N,256] layer-1 out (fp32)
    float* enc = (float*)d_out + NR;                // [N,256] enc_feat_input (fp32)

    // workspace layout
    ushort* xb   = (ushort*)d_ws;                   // bf16 A (x for L0, enc for L1)
    ushort* mb   = xb + NR;                         // bf16 pool msgs
    ushort* aggb = mb + NR;                         // bf16 aggregated
    float*  tmp  = (float*)(aggb + NR);             // fp32 pre-norm h0
    ushort* Bt   = (ushort*)(tmp + NR);             // 6 x [256,256] bf16 W^T
    int* row_ptr = (int*)(Bt + 6 * 256 * 256);      // N+1
    int* cursor  = row_ptr + (N + 1);
    int* deg     = cursor + N;
    int* incl    = deg + N;                         // N (inclusive scan scratch)
    int* partials= incl + N;                        // <=1024
    int* esrc    = partials + 1024;                 // E

    ushort* Bt_pool0  = Bt + 0 * 65536;
    ushort* Bt_self0  = Bt + 1 * 65536;
    ushort* Bt_neigh0 = Bt + 2 * 65536;
    ushort* Bt_pool1  = Bt + 3 * 65536;
    ushort* Bt_self1  = Bt + 4 * 65536;
    ushort* Bt_neigh1 = Bt + 5 * 65536;

    const dim3 gemm_grid((N + 127) / 128, 2);
    const int  q_blocks    = ((E >> 2) + 1 + 255) / 256;   // int4 edge kernels
    const int  node_blocks = (N + 3) / 4;
    const int  conv_blocks = (int)((NR / 4 + 255) / 256);
    const int  scan_blocks = (N + 1023) / 1024;

    // ---------------- one-time conversions ----------------
    WP6 wp;
    wp.p[0] = { W_pool0,  Bt_pool0  };
    wp.p[1] = { W_self0,  Bt_self0  };
    wp.p[2] = { W_neigh0, Bt_neigh0 };
    wp.p[3] = { W_pool1,  Bt_pool1  };
    wp.p[4] = { W_self1,  Bt_self1  };
    wp.p[5] = { W_neigh1, Bt_neigh1 };
    wtrans_kernel<<<dim3(8, 8, 6), 256, 0, stream>>>(wp);
    f2bf_kernel<<<conv_blocks, 256, 0, stream>>>(x, xb, (int)(NR / 4));

    // ---------------- CSR build ----------------
    hipMemsetAsync(deg, 0, (size_t)N * sizeof(int), stream);
    hist_kernel<<<q_blocks, 256, 0, stream>>>(dst, deg, E);
    blockscan_kernel<<<scan_blocks, 1024, 0, stream>>>(deg, incl, partials, N);
    scanp_kernel<<<1, 1024, 0, stream>>>(partials, scan_blocks);
    finalize_kernel<<<scan_blocks, 1024, 0, stream>>>(deg, incl, partials,
                                                      row_ptr, cursor, N, E);
    bucket_kernel<<<q_blocks, 256, 0, stream>>>(src, dst, cursor, esrc, E);

    // ---------------- layer 0 ----------------
    mfma_gemm_kernel<0,1,1><<<gemm_grid, 256, 0, stream>>>(xb, Bt_pool0, nullptr, nullptr,
                                                           b_pool0, mb, N);
    agg_max_kernel<<<node_blocks, 256, 0, stream>>>(row_ptr, esrc, mb, aggb, N);
    mfma_gemm_kernel<1,1,0><<<gemm_grid, 256, 0, stream>>>(xb, Bt_self0, aggb, Bt_neigh0,
                                                           b0, tmp, N);
    l2norm_kernel<<<node_blocks, 256, 0, stream>>>(tmp, enc, xb, N);  // xb now holds enc bf16

    // ---------------- layer 1 ----------------
    mfma_gemm_kernel<0,1,1><<<gemm_grid, 256, 0, stream>>>(xb, Bt_pool1, nullptr, nullptr,
                                                           b_pool1, mb, N);
    agg_max_kernel<<<node_blocks, 256, 0, stream>>>(row_ptr, esrc, mb, aggb, N);
    mfma_gemm_kernel<1,0,0><<<gemm_grid, 256, 0, stream>>>(xb, Bt_self1, aggb, Bt_neigh1,
                                                           b1, h1, N);
}

// Round 13
// 357.414 us; speedup vs baseline: 1.1542x; 1.1542x over previous
//
#include <hip/hip_runtime.h>
#include <cstddef>

#define D256 256

typedef __attribute__((ext_vector_type(8))) short bf16x8;
typedef __attribute__((ext_vector_type(4))) float f32x4;

// global -> LDS direct (16B per lane, wave-uniform LDS base + lane*16)
#define GLOAD16(gptr, lptr)                                                         \
    __builtin_amdgcn_global_load_lds(                                               \
        (const __attribute__((address_space(1))) unsigned int*)(gptr),              \
        (__attribute__((address_space(3))) unsigned int*)(lptr), 16, 0, 0)

__device__ __forceinline__ ushort f2bf(float f) {
    unsigned u = __float_as_uint(f);
    return (ushort)((u + 0x7FFFu + ((u >> 16) & 1u)) >> 16);   // RNE
}
__device__ __forceinline__ ushort umax16(ushort a, ushort b) { return a > b ? a : b; }
__device__ __forceinline__ ushort4 vmax4(ushort4 a, ushort4 b) {
    return make_ushort4(umax16(a.x, b.x), umax16(a.y, b.y),
                        umax16(a.z, b.z), umax16(a.w, b.w));
}

// ---------------- MFMA GEMM: out = act( A@Bt^T (+ A2@Bt2^T) + bias ) ----------------
// A [M,256] bf16 row-major; Bt [256,256] bf16 = W^T (row n = output col, K-contiguous).
// 128x128 tile, 4 waves (2x2), 64x64/wave, BK=32, 16x16x32 MFMA.
// 2-phase double-buffered global_load_lds staging (A,B[,A2,B2] all in LDS — R12
// showed per-lane strided B-from-global loses to coalesced staging).
// 1D grid + bijective XCD-chunked swizzle (m204): A-panel partners (same bx,
// by=0/1) are adjacent within an XCD chunk -> A panel read once per L2;
// per-XCD working set ~3MB A-panels + 128KB weights < 4MB L2.
// Swapped-operand mfma(bf, af): D frag = (m = lane&15, n = kg*4 + reg)
// -> float4/ushort4 epilogue stores.
template<int DUAL, int RELU, int OUT_BF16>
__global__ __launch_bounds__(256)
void mfma_gemm_kernel(const ushort* __restrict__ A, const ushort* __restrict__ Bt,
                      const ushort* __restrict__ A2, const ushort* __restrict__ Bt2,
                      const float* __restrict__ bias, void* __restrict__ outp, int M)
{
    constexpr int TILES = DUAL ? 4 : 2;          // A,B[,A2,B2]
    constexpr int BUFSZ = TILES * 4096;          // ushorts per buffer
    __shared__ ushort smem[2 * BUFSZ];

    // bijective XCD swizzle (nwg need not be a multiple of 8)
    const int nwg  = gridDim.x;
    const int q    = nwg >> 3, r = nwg & 7;
    const int xcd  = blockIdx.x & 7, jj = blockIdx.x >> 3;
    const int wgid = (xcd < r ? xcd * (q + 1) : r * (q + 1) + (xcd - r) * q) + jj;

    const int t    = threadIdx.x;
    const int m0   = (wgid >> 1) * 128;
    const int n0   = (wgid & 1) * 128;
    const int lane = t & 63;
    const int wave = t >> 6;
    const int wr   = (wave >> 1) * 64;   // wave row base in tile
    const int wc   = (wave & 1) * 64;    // wave col base in tile
    const int lr   = lane & 15;
    const int kg   = lane >> 4;          // k-group 0..3

    // staging: wave stages rows [wave*32, wave*32+32) of each tile, 2 insts x 16 rows
    const int lrow  = lane >> 2;         // row within a 16-row instruction
    const int lch   = lane & 3;          // 16B chunk within the 64B row
    const int srow0 = wave * 32;

    f32x4 acc[4][4];
#pragma unroll
    for (int i = 0; i < 4; ++i)
#pragma unroll
        for (int j = 0; j < 4; ++j) acc[i][j] = (f32x4)(0.0f);

    // issue the staging loads for K-step k0 into buffer `buf`
    auto STAGE = [&](int buf, int k0) {
        ushort* const base = smem + buf * BUFSZ;
#pragma unroll
        for (int i = 0; i < 2; ++i) {
            const int r2  = srow0 + i * 16;
            const int ar  = m0 + r2 + lrow;
            const int arc = ar < M ? ar : (M - 1);          // clamp tail rows
            const size_t ga = (size_t)arc * D256 + k0 + lch * 8;
            const size_t gb = (size_t)(n0 + r2 + lrow) * D256 + k0 + lch * 8;
            GLOAD16(A + ga, base + r2 * 32);
            GLOAD16(Bt + gb, base + 4096 + r2 * 32);
            if (DUAL) {
                GLOAD16(A2 + ga, base + 8192 + r2 * 32);
                GLOAD16(Bt2 + gb, base + 12288 + r2 * 32);
            }
        }
    };

    STAGE(0, 0);                                  // prologue prefetch
#pragma unroll
    for (int ks = 0; ks < 8; ++ks) {              // 8 K-steps of 32
        const int cur = ks & 1;
        __syncthreads();   // drains vmcnt(0): buf[cur] ready; prev reads of buf[cur^1] done
        if (ks < 7) STAGE(cur ^ 1, (ks + 1) * 32);   // overlap with MFMA below

        ushort* const base = smem + cur * BUFSZ;
        bf16x8 af[4], bf[4];
#pragma unroll
        for (int mi = 0; mi < 4; ++mi)
            af[mi] = *(const bf16x8*)&base[(wr + mi * 16 + lr) * 32 + kg * 8];
#pragma unroll
        for (int ni = 0; ni < 4; ++ni)
            bf[ni] = *(const bf16x8*)&base[4096 + (wc + ni * 16 + lr) * 32 + kg * 8];
#pragma unroll
        for (int mi = 0; mi < 4; ++mi)
#pragma unroll
            for (int ni = 0; ni < 4; ++ni)
                acc[mi][ni] = __builtin_amdgcn_mfma_f32_16x16x32_bf16(
                    bf[ni], af[mi], acc[mi][ni], 0, 0, 0);   // swapped operands
        if (DUAL) {
            bf16x8 af2[4], bf2[4];
#pragma unroll
            for (int mi = 0; mi < 4; ++mi)
                af2[mi] = *(const bf16x8*)&base[8192 + (wr + mi * 16 + lr) * 32 + kg * 8];
#pragma unroll
            for (int ni = 0; ni < 4; ++ni)
                bf2[ni] = *(const bf16x8*)&base[12288 + (wc + ni * 16 + lr) * 32 + kg * 8];
#pragma unroll
            for (int mi = 0; mi < 4; ++mi)
#pragma unroll
                for (int ni = 0; ni < 4; ++ni)
                    acc[mi][ni] = __builtin_amdgcn_mfma_f32_16x16x32_bf16(
                        bf2[ni], af2[mi], acc[mi][ni], 0, 0, 0);
        }
    }

    // Swapped C/D layout: m = lane&15, n = kg*4 + reg  -> vector stores
#pragma unroll
    for (int ni = 0; ni < 4; ++ni) {
        const int colb = n0 + wc + ni * 16 + kg * 4;
        const float4 bb = *(const float4*)(bias + colb);
#pragma unroll
        for (int mi = 0; mi < 4; ++mi) {
            const int row = m0 + wr + mi * 16 + lr;
            if (row < M) {
                const f32x4 a = acc[mi][ni];
                float4 o;
                o.x = a[0] + bb.x;
                o.y = a[1] + bb.y;
                o.z = a[2] + bb.z;
                o.w = a[3] + bb.w;
                if (RELU) {
                    o.x = fmaxf(o.x, 0.f); o.y = fmaxf(o.y, 0.f);
                    o.z = fmaxf(o.z, 0.f); o.w = fmaxf(o.w, 0.f);
                }
                if (OUT_BF16) {
                    ushort4 ob;
                    ob.x = f2bf(o.x); ob.y = f2bf(o.y);
                    ob.z = f2bf(o.z); ob.w = f2bf(o.w);
                    *(ushort4*)((ushort*)outp + (size_t)row * D256 + colb) = ob;
                } else {
                    *(float4*)((float*)outp + (size_t)row * D256 + colb) = o;
                }
            }
        }
    }
}

// ---------------- fp32 -> bf16 convert ----------------
__global__ __launch_bounds__(256)
void f2bf_kernel(const float* __restrict__ in, ushort* __restrict__ out, int n4)
{
    const int i = blockIdx.x * 256 + threadIdx.x;
    if (i >= n4) return;
    const float4 v = ((const float4*)in)[i];
    ushort4 o;
    o.x = f2bf(v.x); o.y = f2bf(v.y); o.z = f2bf(v.z); o.w = f2bf(v.w);
    ((ushort4*)out)[i] = o;
}

// ---------------- weight transpose+convert: Bt[n][k] = bf16(W[k][n]) ----------------
struct WP  { const float* w; ushort* o; };
struct WP6 { WP p[6]; };
__global__ __launch_bounds__(256)
void wtrans_kernel(WP6 ps)
{
    const float* __restrict__ W = ps.p[blockIdx.z].w;
    ushort* __restrict__ O      = ps.p[blockIdx.z].o;
    __shared__ float sm[32][33];
    const int tx = threadIdx.x & 31, ty = threadIdx.x >> 5;
    const int k0 = blockIdx.x * 32, n0 = blockIdx.y * 32;
#pragma unroll
    for (int i = 0; i < 4; ++i)
        sm[ty + i * 8][tx] = W[(size_t)(k0 + ty + i * 8) * D256 + n0 + tx];
    __syncthreads();
#pragma unroll
    for (int i = 0; i < 4; ++i)
        O[(size_t)(n0 + ty + i * 8) * D256 + k0 + tx] = f2bf(sm[tx][ty + i * 8]);
}

// ---------------- CSR build: histogram -> hierarchical scan -> bucket scatter ----------------
// int4-vectorized edge reads (4 edges/thread); atomic count unchanged.
__global__ __launch_bounds__(256)
void hist_kernel(const int* __restrict__ dst, int* __restrict__ deg, int E)
{
    const int nq = E >> 2;
    const int i  = blockIdx.x * 256 + threadIdx.x;
    if (i < nq) {
        const int4 d = ((const int4*)dst)[i];
        atomicAdd(&deg[d.x], 1);
        atomicAdd(&deg[d.y], 1);
        atomicAdd(&deg[d.z], 1);
        atomicAdd(&deg[d.w], 1);
    } else if (i == nq) {
        for (int e = nq * 4; e < E; ++e) atomicAdd(&deg[dst[e]], 1);
    }
}

// per-block (1024 elems) inclusive scan: wave shfl scan + 16-wave LDS combine
__global__ __launch_bounds__(1024)
void blockscan_kernel(const int* __restrict__ deg, int* __restrict__ incl,
                      int* __restrict__ partials, int N)
{
    __shared__ int wt[16];
    const int i    = blockIdx.x * 1024 + threadIdx.x;
    const int lane = threadIdx.x & 63;
    const int wv   = threadIdx.x >> 6;
    const int v    = (i < N) ? deg[i] : 0;
    int s = v;
#pragma unroll
    for (int o = 1; o < 64; o <<= 1) {
        const int t = __shfl_up(s, o);
        if (lane >= o) s += t;
    }
    if (lane == 63) wt[wv] = s;
    __syncthreads();
    if (wv == 0 && lane < 16) {
        const int w = wt[lane];
        int ws = w;
#pragma unroll
        for (int o = 1; o < 16; o <<= 1) {
            const int t = __shfl_up(ws, o);
            if (lane >= o) ws += t;
        }
        wt[lane] = ws - w;   // exclusive wave offset
    }
    __syncthreads();
    s += wt[wv];
    if (i < N) incl[i] = s;
    if (threadIdx.x == 1023) partials[blockIdx.x] = s;
}

// scan the (<=1024) block totals into exclusive offsets; single block
__global__ __launch_bounds__(1024)
void scanp_kernel(int* __restrict__ partials, int nb)
{
    __shared__ int sm[1024];
    const int v = (threadIdx.x < (unsigned)nb) ? partials[threadIdx.x] : 0;
    sm[threadIdx.x] = v;
    __syncthreads();
#pragma unroll
    for (int off = 1; off < 1024; off <<= 1) {
        const int t = (threadIdx.x >= (unsigned)off) ? sm[threadIdx.x - off] : 0;
        __syncthreads();
        sm[threadIdx.x] += t;
        __syncthreads();
    }
    if (threadIdx.x < (unsigned)nb) partials[threadIdx.x] = sm[threadIdx.x] - v;
}

__global__ __launch_bounds__(1024)
void finalize_kernel(const int* __restrict__ deg, const int* __restrict__ incl,
                     const int* __restrict__ partials, int* __restrict__ row_ptr,
                     int* __restrict__ cursor, int N, int E)
{
    const int i = blockIdx.x * 1024 + threadIdx.x;
    if (i < N) {
        const int ex = partials[blockIdx.x] + incl[i] - deg[i];
        row_ptr[i] = ex;
        cursor[i]  = ex;
    }
    if (i == 0) row_ptr[N] = E;
}

__global__ __launch_bounds__(256)
void bucket_kernel(const int* __restrict__ src, const int* __restrict__ dst,
                   int* __restrict__ cursor, int* __restrict__ esrc, int E)
{
    const int nq = E >> 2;
    const int i  = blockIdx.x * 256 + threadIdx.x;
    if (i < nq) {
        const int4 d = ((const int4*)dst)[i];
        const int4 s = ((const int4*)src)[i];
        esrc[atomicAdd(&cursor[d.x], 1)] = s.x;
        esrc[atomicAdd(&cursor[d.y], 1)] = s.y;
        esrc[atomicAdd(&cursor[d.z], 1)] = s.z;
        esrc[atomicAdd(&cursor[d.w], 1)] = s.w;
    } else if (i == nq) {
        for (int e = nq * 4; e < E; ++e)
            esrc[atomicAdd(&cursor[dst[e]], 1)] = src[e];
    }
}

// ---------------- node-parallel segment max over bf16 rows ----------------
// m >= 0 (relu), so unsigned-short compare == float compare; 0 = identity.
// Wave-per-node: 64 lanes read one full 512B row coalesced.
__global__ __launch_bounds__(256)
void agg_max_kernel(const int* __restrict__ row_ptr, const int* __restrict__ esrc,
                    const ushort* __restrict__ m, ushort* __restrict__ agg, int N)
{
    const int wid  = (int)(((size_t)blockIdx.x * 256 + threadIdx.x) >> 6);
    const int lane = threadIdx.x & 63;
    if (wid >= N) return;
    const int beg = row_ptr[wid];
    const int end = row_ptr[wid + 1];
    const size_t off = (size_t)(lane * 4);

    ushort4 a0 = make_ushort4(0, 0, 0, 0);
    ushort4 a1 = a0, a2 = a0, a3 = a0;
    int e = beg;
    for (; e + 8 <= end; e += 8) {
        int s[8];
#pragma unroll
        for (int q = 0; q < 8; ++q) s[q] = esrc[e + q];
        ushort4 v[8];
#pragma unroll
        for (int q = 0; q < 8; ++q)
            v[q] = *(const ushort4*)(m + (size_t)s[q] * D256 + off);
        a0 = vmax4(a0, vmax4(v[0], v[4]));
        a1 = vmax4(a1, vmax4(v[1], v[5]));
        a2 = vmax4(a2, vmax4(v[2], v[6]));
        a3 = vmax4(a3, vmax4(v[3], v[7]));
    }
    for (; e + 2 <= end; e += 2) {
        const int s0 = esrc[e];
        const int s1 = esrc[e + 1];
        const ushort4 v0 = *(const ushort4*)(m + (size_t)s0 * D256 + off);
        const ushort4 v1 = *(const ushort4*)(m + (size_t)s1 * D256 + off);
        a0 = vmax4(a0, v0);
        a1 = vmax4(a1, v1);
    }
    if (e < end) {
        const ushort4 v0 = *(const ushort4*)(m + (size_t)esrc[e] * D256 + off);
        a2 = vmax4(a2, v0);
    }
    const ushort4 r = vmax4(vmax4(a0, a1), vmax4(a2, a3));
    *(ushort4*)(agg + (size_t)wid * D256 + off) = r;
}

// ------------- row-wise L2 normalize: fp32 out + bf16 copy -------------
__global__ __launch_bounds__(256)
void l2norm_kernel(const float* __restrict__ in, float* __restrict__ out_f,
                   ushort* __restrict__ out_b, int M)
{
    const int wid  = (int)(((size_t)blockIdx.x * 256 + threadIdx.x) >> 6);
    const int lane = threadIdx.x & 63;
    if (wid >= M) return;
    const float4 v = *(const float4*)(in + (size_t)wid * D256 + lane * 4);
    float ss = v.x * v.x + v.y * v.y + v.z * v.z + v.w * v.w;
#pragma unroll
    for (int o = 32; o >= 1; o >>= 1) ss += __shfl_xor(ss, o);
    const float inv = 1.0f / fmaxf(sqrtf(ss), 1e-12f);
    float4 o4;
    o4.x = v.x * inv; o4.y = v.y * inv; o4.z = v.z * inv; o4.w = v.w * inv;
    *(float4*)(out_f + (size_t)wid * D256 + lane * 4) = o4;
    ushort4 ob;
    ob.x = f2bf(o4.x); ob.y = f2bf(o4.y); ob.z = f2bf(o4.z); ob.w = f2bf(o4.w);
    *(ushort4*)(out_b + (size_t)wid * D256 + lane * 4) = ob;
}

extern "C" void kernel_launch(void* const* d_in, const int* in_sizes, int n_in,
                              void* d_out, int out_size, void* d_ws, size_t ws_size,
                              hipStream_t stream)
{
    const float* x        = (const float*)d_in[0];
    const int*   src      = (const int*)  d_in[1];
    const int*   dst      = (const int*)  d_in[2];
    const float* W_pool0  = (const float*)d_in[3];
    const float* b_pool0  = (const float*)d_in[4];
    const float* W_self0  = (const float*)d_in[5];
    const float* W_neigh0 = (const float*)d_in[6];
    const float* b0       = (const float*)d_in[7];
    const float* W_pool1  = (const float*)d_in[8];
    const float* b_pool1  = (const float*)d_in[9];
    const float* W_self1  = (const float*)d_in[10];
    const float* W_neigh1 = (const float*)d_in[11];
    const float* b1       = (const float*)d_in[12];

    const int N = in_sizes[0] / D256;
    const int E = in_sizes[1];
    const size_t NR = (size_t)N * D256;   // elems per node matrix

    float* h1  = (float*)d_out;                     // [N,256] layer-1 out (fp32)
    float* enc = (float*)d_out + NR;                // [N,256] enc_feat_input (fp32)

    // workspace layout
    ushort* xb   = (ushort*)d_ws;                   // bf16 A (x for L0, enc for L1)
    ushort* mb   = xb + NR;                         // bf16 pool msgs
    ushort* aggb = mb + NR;                         // bf16 aggregated
    float*  tmp  = (float*)(aggb + NR);             // fp32 pre-norm h0
    ushort* Bt   = (ushort*)(tmp + NR);             // 6 x [256,256] bf16 W^T
    int* row_ptr = (int*)(Bt + 6 * 256 * 256);      // N+1
    int* cursor  = row_ptr + (N + 1);
    int* deg     = cursor + N;
    int* incl    = deg + N;                         // N (inclusive scan scratch)
    int* partials= incl + N;                        // <=1024
    int* esrc    = partials + 1024;                 // E

    ushort* Bt_pool0  = Bt + 0 * 65536;
    ushort* Bt_self0  = Bt + 1 * 65536;
    ushort* Bt_neigh0 = Bt + 2 * 65536;
    ushort* Bt_pool1  = Bt + 3 * 65536;
    ushort* Bt_self1  = Bt + 4 * 65536;
    ushort* Bt_neigh1 = Bt + 5 * 65536;

    const int  gemm_blocks = ((N + 127) / 128) * 2;        // 1D swizzled grid
    const int  q_blocks    = ((E >> 2) + 1 + 255) / 256;   // int4 edge kernels
    const int  node_blocks = (N + 3) / 4;
    const int  conv_blocks = (int)((NR / 4 + 255) / 256);
    const int  scan_blocks = (N + 1023) / 1024;

    // ---------------- one-time conversions ----------------
    WP6 wp;
    wp.p[0] = { W_pool0,  Bt_pool0  };
    wp.p[1] = { W_self0,  Bt_self0  };
    wp.p[2] = { W_neigh0, Bt_neigh0 };
    wp.p[3] = { W_pool1,  Bt_pool1  };
    wp.p[4] = { W_self1,  Bt_self1  };
    wp.p[5] = { W_neigh1, Bt_neigh1 };
    wtrans_kernel<<<dim3(8, 8, 6), 256, 0, stream>>>(wp);
    f2bf_kernel<<<conv_blocks, 256, 0, stream>>>(x, xb, (int)(NR / 4));

    // ---------------- CSR build ----------------
    hipMemsetAsync(deg, 0, (size_t)N * sizeof(int), stream);
    hist_kernel<<<q_blocks, 256, 0, stream>>>(dst, deg, E);
    blockscan_kernel<<<scan_blocks, 1024, 0, stream>>>(deg, incl, partials, N);
    scanp_kernel<<<1, 1024, 0, stream>>>(partials, scan_blocks);
    finalize_kernel<<<scan_blocks, 1024, 0, stream>>>(deg, incl, partials,
                                                      row_ptr, cursor, N, E);
    bucket_kernel<<<q_blocks, 256, 0, stream>>>(src, dst, cursor, esrc, E);

    // ---------------- layer 0 ----------------
    mfma_gemm_kernel<0,1,1><<<gemm_blocks, 256, 0, stream>>>(xb, Bt_pool0, nullptr, nullptr,
                                                             b_pool0, mb, N);
    agg_max_kernel<<<node_blocks, 256, 0, stream>>>(row_ptr, esrc, mb, aggb, N);
    mfma_gemm_kernel<1,1,0><<<gemm_blocks, 256, 0, stream>>>(xb, Bt_self0, aggb, Bt_neigh0,
                                                             b0, tmp, N);
    l2norm_kernel<<<node_blocks, 256, 0, stream>>>(tmp, enc, xb, N);  // xb now holds enc bf16

    // ---------------- layer 1 ----------------
    mfma_gemm_kernel<0,1,1><<<gemm_blocks, 256, 0, stream>>>(xb, Bt_pool1, nullptr, nullptr,
                                                             b_pool1, mb, N);
    agg_max_kernel<<<node_blocks, 256, 0, stream>>>(row_ptr, esrc, mb, aggb, N);
    mfma_gemm_kernel<1,0,0><<<gemm_blocks, 256, 0, stream>>>(xb, Bt_self1, aggb, Bt_neigh1,
                                                             b1, h1, N);
}

// Round 14
// 355.357 us; speedup vs baseline: 1.1609x; 1.0058x over previous
//
#include <hip/hip_runtime.h>
#include <cstddef>

#define D256 256

typedef __attribute__((ext_vector_type(8))) short bf16x8;
typedef __attribute__((ext_vector_type(4))) float f32x4;

// global -> LDS direct (16B per lane, wave-uniform LDS base + lane*16)
#define GLOAD16(gptr, lptr)                                                         \
    __builtin_amdgcn_global_load_lds(                                               \
        (const __attribute__((address_space(1))) unsigned int*)(gptr),              \
        (__attribute__((address_space(3))) unsigned int*)(lptr), 16, 0, 0)

__device__ __forceinline__ ushort f2bf(float f) {
    unsigned u = __float_as_uint(f);
    return (ushort)((u + 0x7FFFu + ((u >> 16) & 1u)) >> 16);   // RNE
}
__device__ __forceinline__ ushort umax16(ushort a, ushort b) { return a > b ? a : b; }
__device__ __forceinline__ ushort4 vmax4(ushort4 a, ushort4 b) {
    return make_ushort4(umax16(a.x, b.x), umax16(a.y, b.y),
                        umax16(a.z, b.z), umax16(a.w, b.w));
}

// ---------------- MFMA GEMM: out = act( A@Bt^T (+ A2@Bt2^T) + bias ) ----------------
// 128x128 tile, 4 waves (2x2), 64x64/wave, BK=32, 16x16x32 MFMA.
// 2-phase dbuf global_load_lds staging; 1D grid + bijective XCD swizzle (m204).
// Swapped-operand mfma(bf, af): D frag = (m = lane&15, n = kg*4 + reg).
template<int DUAL, int RELU, int OUT_BF16>
__global__ __launch_bounds__(256)
void mfma_gemm_kernel(const ushort* __restrict__ A, const ushort* __restrict__ Bt,
                      const ushort* __restrict__ A2, const ushort* __restrict__ Bt2,
                      const float* __restrict__ bias, void* __restrict__ outp, int M)
{
    constexpr int TILES = DUAL ? 4 : 2;          // A,B[,A2,B2]
    constexpr int BUFSZ = TILES * 4096;          // ushorts per buffer
    __shared__ ushort smem[2 * BUFSZ];

    // bijective XCD swizzle (nwg need not be a multiple of 8)
    const int nwg  = gridDim.x;
    const int q    = nwg >> 3, r = nwg & 7;
    const int xcd  = blockIdx.x & 7, jj = blockIdx.x >> 3;
    const int wgid = (xcd < r ? xcd * (q + 1) : r * (q + 1) + (xcd - r) * q) + jj;

    const int t    = threadIdx.x;
    const int m0   = (wgid >> 1) * 128;
    const int n0   = (wgid & 1) * 128;
    const int lane = t & 63;
    const int wave = t >> 6;
    const int wr   = (wave >> 1) * 64;
    const int wc   = (wave & 1) * 64;
    const int lr   = lane & 15;
    const int kg   = lane >> 4;

    const int lrow  = lane >> 2;
    const int lch   = lane & 3;
    const int srow0 = wave * 32;

    f32x4 acc[4][4];
#pragma unroll
    for (int i = 0; i < 4; ++i)
#pragma unroll
        for (int j = 0; j < 4; ++j) acc[i][j] = (f32x4)(0.0f);

    auto STAGE = [&](int buf, int k0) {
        ushort* const base = smem + buf * BUFSZ;
#pragma unroll
        for (int i = 0; i < 2; ++i) {
            const int r2  = srow0 + i * 16;
            const int ar  = m0 + r2 + lrow;
            const int arc = ar < M ? ar : (M - 1);
            const size_t ga = (size_t)arc * D256 + k0 + lch * 8;
            const size_t gb = (size_t)(n0 + r2 + lrow) * D256 + k0 + lch * 8;
            GLOAD16(A + ga, base + r2 * 32);
            GLOAD16(Bt + gb, base + 4096 + r2 * 32);
            if (DUAL) {
                GLOAD16(A2 + ga, base + 8192 + r2 * 32);
                GLOAD16(Bt2 + gb, base + 12288 + r2 * 32);
            }
        }
    };

    STAGE(0, 0);
#pragma unroll
    for (int ks = 0; ks < 8; ++ks) {
        const int cur = ks & 1;
        __syncthreads();
        if (ks < 7) STAGE(cur ^ 1, (ks + 1) * 32);

        ushort* const base = smem + cur * BUFSZ;
        bf16x8 af[4], bf[4];
#pragma unroll
        for (int mi = 0; mi < 4; ++mi)
            af[mi] = *(const bf16x8*)&base[(wr + mi * 16 + lr) * 32 + kg * 8];
#pragma unroll
        for (int ni = 0; ni < 4; ++ni)
            bf[ni] = *(const bf16x8*)&base[4096 + (wc + ni * 16 + lr) * 32 + kg * 8];
#pragma unroll
        for (int mi = 0; mi < 4; ++mi)
#pragma unroll
            for (int ni = 0; ni < 4; ++ni)
                acc[mi][ni] = __builtin_amdgcn_mfma_f32_16x16x32_bf16(
                    bf[ni], af[mi], acc[mi][ni], 0, 0, 0);
        if (DUAL) {
            bf16x8 af2[4], bf2[4];
#pragma unroll
            for (int mi = 0; mi < 4; ++mi)
                af2[mi] = *(const bf16x8*)&base[8192 + (wr + mi * 16 + lr) * 32 + kg * 8];
#pragma unroll
            for (int ni = 0; ni < 4; ++ni)
                bf2[ni] = *(const bf16x8*)&base[12288 + (wc + ni * 16 + lr) * 32 + kg * 8];
#pragma unroll
            for (int mi = 0; mi < 4; ++mi)
#pragma unroll
                for (int ni = 0; ni < 4; ++ni)
                    acc[mi][ni] = __builtin_amdgcn_mfma_f32_16x16x32_bf16(
                        bf2[ni], af2[mi], acc[mi][ni], 0, 0, 0);
        }
    }

#pragma unroll
    for (int ni = 0; ni < 4; ++ni) {
        const int colb = n0 + wc + ni * 16 + kg * 4;
        const float4 bb = *(const float4*)(bias + colb);
#pragma unroll
        for (int mi = 0; mi < 4; ++mi) {
            const int row = m0 + wr + mi * 16 + lr;
            if (row < M) {
                const f32x4 a = acc[mi][ni];
                float4 o;
                o.x = a[0] + bb.x;
                o.y = a[1] + bb.y;
                o.z = a[2] + bb.z;
                o.w = a[3] + bb.w;
                if (RELU) {
                    o.x = fmaxf(o.x, 0.f); o.y = fmaxf(o.y, 0.f);
                    o.z = fmaxf(o.z, 0.f); o.w = fmaxf(o.w, 0.f);
                }
                if (OUT_BF16) {
                    ushort4 ob;
                    ob.x = f2bf(o.x); ob.y = f2bf(o.y);
                    ob.z = f2bf(o.z); ob.w = f2bf(o.w);
                    *(ushort4*)((ushort*)outp + (size_t)row * D256 + colb) = ob;
                } else {
                    *(float4*)((float*)outp + (size_t)row * D256 + colb) = o;
                }
            }
        }
    }
}

// ------ fused dual GEMM + relu + row-l2norm: enc_f = l2n(relu(A@Bt^T + A2@Bt2^T + b)),
// ------ enc_b = bf16(enc_f). Tile 128 rows x FULL 256 cols so each block owns whole
// ------ rows (norm is block-local; enc_b may alias A: block writes only its own A rows,
// ------ and only after the K-loop). 4 waves of 64x128; single-buffered 48KB LDS.
__global__ __launch_bounds__(256)
void mfma_dual_l2n_kernel(const ushort* A, const ushort* __restrict__ Bt,
                          const ushort* __restrict__ A2, const ushort* __restrict__ Bt2,
                          const float* __restrict__ bias,
                          float* __restrict__ enc_f, ushort* enc_b, int M)
{
    __shared__ ushort smem[24576];        // A:0 | B:4096 | A2:12288 | B2:16384
    __shared__ float  ssq_lds[128][2];

    const int t    = threadIdx.x;
    const int m0   = blockIdx.x * 128;
    const int lane = t & 63;
    const int wave = t >> 6;
    const int wr   = (wave >> 1) * 64;    // rows 0-63 / 64-127
    const int wc   = (wave & 1) * 128;    // cols 0-127 / 128-255
    const int lr   = lane & 15;
    const int kg   = lane >> 4;
    const int lrow = lane >> 2;
    const int lch  = lane & 3;

    f32x4 acc[4][8];
#pragma unroll
    for (int i = 0; i < 4; ++i)
#pragma unroll
        for (int j = 0; j < 8; ++j) acc[i][j] = (f32x4)(0.0f);

    for (int ks = 0; ks < 8; ++ks) {
        const int k0 = ks * 32;
        __syncthreads();                  // previous step's LDS reads done
        // stage A/A2 (2 insts each) and B/B2 (4 insts each) per wave
#pragma unroll
        for (int i = 0; i < 2; ++i) {
            const int r2  = wave * 32 + i * 16;
            const int ar  = m0 + r2 + lrow;
            const int arc = ar < M ? ar : (M - 1);
            const size_t ga = (size_t)arc * D256 + k0 + lch * 8;
            GLOAD16(A + ga, smem + r2 * 32);
            GLOAD16(A2 + ga, smem + 12288 + r2 * 32);
        }
#pragma unroll
        for (int i = 0; i < 4; ++i) {
            const int r2 = wave * 64 + i * 16;
            const size_t gb = (size_t)(r2 + lrow) * D256 + k0 + lch * 8;
            GLOAD16(Bt + gb, smem + 4096 + r2 * 32);
            GLOAD16(Bt2 + gb, smem + 16384 + r2 * 32);
        }
        __syncthreads();                  // vmcnt(0) drained: tiles ready

        bf16x8 af[4];
#pragma unroll
        for (int mi = 0; mi < 4; ++mi)
            af[mi] = *(const bf16x8*)&smem[(wr + mi * 16 + lr) * 32 + kg * 8];
#pragma unroll
        for (int ni = 0; ni < 8; ++ni) {
            const bf16x8 b = *(const bf16x8*)&smem[4096 + (wc + ni * 16 + lr) * 32 + kg * 8];
#pragma unroll
            for (int mi = 0; mi < 4; ++mi)
                acc[mi][ni] = __builtin_amdgcn_mfma_f32_16x16x32_bf16(
                    b, af[mi], acc[mi][ni], 0, 0, 0);
        }
#pragma unroll
        for (int mi = 0; mi < 4; ++mi)
            af[mi] = *(const bf16x8*)&smem[12288 + (wr + mi * 16 + lr) * 32 + kg * 8];
#pragma unroll
        for (int ni = 0; ni < 8; ++ni) {
            const bf16x8 b = *(const bf16x8*)&smem[16384 + (wc + ni * 16 + lr) * 32 + kg * 8];
#pragma unroll
            for (int mi = 0; mi < 4; ++mi)
                acc[mi][ni] = __builtin_amdgcn_mfma_f32_16x16x32_bf16(
                    b, af[mi], acc[mi][ni], 0, 0, 0);
        }
    }

    // epilogue: bias + relu, per-row ssq, cross-kg + cross-wave reduce, scale, store
    float ssq[4] = {0.f, 0.f, 0.f, 0.f};
#pragma unroll
    for (int mi = 0; mi < 4; ++mi)
#pragma unroll
        for (int ni = 0; ni < 8; ++ni) {
            const int colb = wc + ni * 16 + kg * 4;
            const float4 bb = *(const float4*)(bias + colb);
            f32x4 a = acc[mi][ni];
            a[0] = fmaxf(a[0] + bb.x, 0.f);
            a[1] = fmaxf(a[1] + bb.y, 0.f);
            a[2] = fmaxf(a[2] + bb.z, 0.f);
            a[3] = fmaxf(a[3] + bb.w, 0.f);
            acc[mi][ni] = a;
            ssq[mi] += a[0] * a[0] + a[1] * a[1] + a[2] * a[2] + a[3] * a[3];
        }
#pragma unroll
    for (int mi = 0; mi < 4; ++mi) {
        ssq[mi] += __shfl_xor(ssq[mi], 16);
        ssq[mi] += __shfl_xor(ssq[mi], 32);
    }
    __syncthreads();
    if (kg == 0) {
#pragma unroll
        for (int mi = 0; mi < 4; ++mi)
            ssq_lds[wr + mi * 16 + lr][wave & 1] = ssq[mi];
    }
    __syncthreads();
#pragma unroll
    for (int mi = 0; mi < 4; ++mi) {
        const int rrow = wr + mi * 16 + lr;
        const int row  = m0 + rrow;
        const float tot = ssq_lds[rrow][0] + ssq_lds[rrow][1];
        const float inv = 1.0f / fmaxf(sqrtf(tot), 1e-12f);
        if (row < M) {
#pragma unroll
            for (int ni = 0; ni < 8; ++ni) {
                const int colb = wc + ni * 16 + kg * 4;
                const f32x4 a = acc[mi][ni];
                float4 o;
                o.x = a[0] * inv; o.y = a[1] * inv;
                o.z = a[2] * inv; o.w = a[3] * inv;
                *(float4*)(enc_f + (size_t)row * D256 + colb) = o;
                ushort4 ob;
                ob.x = f2bf(o.x); ob.y = f2bf(o.y);
                ob.z = f2bf(o.z); ob.w = f2bf(o.w);
                *(ushort4*)(enc_b + (size_t)row * D256 + colb) = ob;
            }
        }
    }
}

// ---------------- fp32 -> bf16 convert ----------------
__global__ __launch_bounds__(256)
void f2bf_kernel(const float* __restrict__ in, ushort* __restrict__ out, int n4)
{
    const int i = blockIdx.x * 256 + threadIdx.x;
    if (i >= n4) return;
    const float4 v = ((const float4*)in)[i];
    ushort4 o;
    o.x = f2bf(v.x); o.y = f2bf(v.y); o.z = f2bf(v.z); o.w = f2bf(v.w);
    ((ushort4*)out)[i] = o;
}

// ---------------- weight transpose+convert: Bt[n][k] = bf16(W[k][n]) ----------------
struct WP  { const float* w; ushort* o; };
struct WP6 { WP p[6]; };
__global__ __launch_bounds__(256)
void wtrans_kernel(WP6 ps)
{
    const float* __restrict__ W = ps.p[blockIdx.z].w;
    ushort* __restrict__ O      = ps.p[blockIdx.z].o;
    __shared__ float sm[32][33];
    const int tx = threadIdx.x & 31, ty = threadIdx.x >> 5;
    const int k0 = blockIdx.x * 32, n0 = blockIdx.y * 32;
#pragma unroll
    for (int i = 0; i < 4; ++i)
        sm[ty + i * 8][tx] = W[(size_t)(k0 + ty + i * 8) * D256 + n0 + tx];
    __syncthreads();
#pragma unroll
    for (int i = 0; i < 4; ++i)
        O[(size_t)(n0 + ty + i * 8) * D256 + k0 + tx] = f2bf(sm[tx][ty + i * 8]);
}

// ---------------- CSR build: histogram -> hierarchical scan -> bucket scatter ----------------
__global__ __launch_bounds__(256)
void hist_kernel(const int* __restrict__ dst, int* __restrict__ deg, int E)
{
    const int nq = E >> 2;
    const int i  = blockIdx.x * 256 + threadIdx.x;
    if (i < nq) {
        const int4 d = ((const int4*)dst)[i];
        atomicAdd(&deg[d.x], 1);
        atomicAdd(&deg[d.y], 1);
        atomicAdd(&deg[d.z], 1);
        atomicAdd(&deg[d.w], 1);
    } else if (i == nq) {
        for (int e = nq * 4; e < E; ++e) atomicAdd(&deg[dst[e]], 1);
    }
}

__global__ __launch_bounds__(1024)
void blockscan_kernel(const int* __restrict__ deg, int* __restrict__ incl,
                      int* __restrict__ partials, int N)
{
    __shared__ int wt[16];
    const int i    = blockIdx.x * 1024 + threadIdx.x;
    const int lane = threadIdx.x & 63;
    const int wv   = threadIdx.x >> 6;
    const int v    = (i < N) ? deg[i] : 0;
    int s = v;
#pragma unroll
    for (int o = 1; o < 64; o <<= 1) {
        const int t = __shfl_up(s, o);
        if (lane >= o) s += t;
    }
    if (lane == 63) wt[wv] = s;
    __syncthreads();
    if (wv == 0 && lane < 16) {
        const int w = wt[lane];
        int ws = w;
#pragma unroll
        for (int o = 1; o < 16; o <<= 1) {
            const int t = __shfl_up(ws, o);
            if (lane >= o) ws += t;
        }
        wt[lane] = ws - w;
    }
    __syncthreads();
    s += wt[wv];
    if (i < N) incl[i] = s;
    if (threadIdx.x == 1023) partials[blockIdx.x] = s;
}

__global__ __launch_bounds__(1024)
void scanp_kernel(int* __restrict__ partials, int nb)
{
    __shared__ int sm[1024];
    const int v = (threadIdx.x < (unsigned)nb) ? partials[threadIdx.x] : 0;
    sm[threadIdx.x] = v;
    __syncthreads();
#pragma unroll
    for (int off = 1; off < 1024; off <<= 1) {
        const int t = (threadIdx.x >= (unsigned)off) ? sm[threadIdx.x - off] : 0;
        __syncthreads();
        sm[threadIdx.x] += t;
        __syncthreads();
    }
    if (threadIdx.x < (unsigned)nb) partials[threadIdx.x] = sm[threadIdx.x] - v;
}

__global__ __launch_bounds__(1024)
void finalize_kernel(const int* __restrict__ deg, const int* __restrict__ incl,
                     const int* __restrict__ partials, int* __restrict__ row_ptr,
                     int* __restrict__ cursor, int N, int E)
{
    const int i = blockIdx.x * 1024 + threadIdx.x;
    if (i < N) {
        const int ex = partials[blockIdx.x] + incl[i] - deg[i];
        row_ptr[i] = ex;
        cursor[i]  = ex;
    }
    if (i == 0) row_ptr[N] = E;
}

__global__ __launch_bounds__(256)
void bucket_kernel(const int* __restrict__ src, const int* __restrict__ dst,
                   int* __restrict__ cursor, int* __restrict__ esrc, int E)
{
    const int nq = E >> 2;
    const int i  = blockIdx.x * 256 + threadIdx.x;
    if (i < nq) {
        const int4 d = ((const int4*)dst)[i];
        const int4 s = ((const int4*)src)[i];
        esrc[atomicAdd(&cursor[d.x], 1)] = s.x;
        esrc[atomicAdd(&cursor[d.y], 1)] = s.y;
        esrc[atomicAdd(&cursor[d.z], 1)] = s.z;
        esrc[atomicAdd(&cursor[d.w], 1)] = s.w;
    } else if (i == nq) {
        for (int e = nq * 4; e < E; ++e)
            esrc[atomicAdd(&cursor[dst[e]], 1)] = src[e];
    }
}

// ---------------- node-parallel segment max over bf16 rows ----------------
__global__ __launch_bounds__(256)
void agg_max_kernel(const int* __restrict__ row_ptr, const int* __restrict__ esrc,
                    const ushort* __restrict__ m, ushort* __restrict__ agg, int N)
{
    const int wid  = (int)(((size_t)blockIdx.x * 256 + threadIdx.x) >> 6);
    const int lane = threadIdx.x & 63;
    if (wid >= N) return;
    const int beg = row_ptr[wid];
    const int end = row_ptr[wid + 1];
    const size_t off = (size_t)(lane * 4);

    ushort4 a0 = make_ushort4(0, 0, 0, 0);
    ushort4 a1 = a0, a2 = a0, a3 = a0;
    int e = beg;
    for (; e + 8 <= end; e += 8) {
        int s[8];
#pragma unroll
        for (int q = 0; q < 8; ++q) s[q] = esrc[e + q];
        ushort4 v[8];
#pragma unroll
        for (int q = 0; q < 8; ++q)
            v[q] = *(const ushort4*)(m + (size_t)s[q] * D256 + off);
        a0 = vmax4(a0, vmax4(v[0], v[4]));
        a1 = vmax4(a1, vmax4(v[1], v[5]));
        a2 = vmax4(a2, vmax4(v[2], v[6]));
        a3 = vmax4(a3, vmax4(v[3], v[7]));
    }
    for (; e + 2 <= end; e += 2) {
        const int s0 = esrc[e];
        const int s1 = esrc[e + 1];
        const ushort4 v0 = *(const ushort4*)(m + (size_t)s0 * D256 + off);
        const ushort4 v1 = *(const ushort4*)(m + (size_t)s1 * D256 + off);
        a0 = vmax4(a0, v0);
        a1 = vmax4(a1, v1);
    }
    if (e < end) {
        const ushort4 v0 = *(const ushort4*)(m + (size_t)esrc[e] * D256 + off);
        a2 = vmax4(a2, v0);
    }
    const ushort4 r = vmax4(vmax4(a0, a1), vmax4(a2, a3));
    *(ushort4*)(agg + (size_t)wid * D256 + off) = r;
}

extern "C" void kernel_launch(void* const* d_in, const int* in_sizes, int n_in,
                              void* d_out, int out_size, void* d_ws, size_t ws_size,
                              hipStream_t stream)
{
    const float* x        = (const float*)d_in[0];
    const int*   src      = (const int*)  d_in[1];
    const int*   dst      = (const int*)  d_in[2];
    const float* W_pool0  = (const float*)d_in[3];
    const float* b_pool0  = (const float*)d_in[4];
    const float* W_self0  = (const float*)d_in[5];
    const float* W_neigh0 = (const float*)d_in[6];
    const float* b0       = (const float*)d_in[7];
    const float* W_pool1  = (const float*)d_in[8];
    const float* b_pool1  = (const float*)d_in[9];
    const float* W_self1  = (const float*)d_in[10];
    const float* W_neigh1 = (const float*)d_in[11];
    const float* b1       = (const float*)d_in[12];

    const int N = in_sizes[0] / D256;
    const int E = in_sizes[1];
    const size_t NR = (size_t)N * D256;

    float* h1  = (float*)d_out;                     // [N,256] layer-1 out (fp32)
    float* enc = (float*)d_out + NR;                // [N,256] enc_feat_input (fp32)

    ushort* xb   = (ushort*)d_ws;                   // bf16 A (x for L0, enc for L1)
    ushort* mb   = xb + NR;                         // bf16 pool msgs
    ushort* aggb = mb + NR;                         // bf16 aggregated
    float*  tmp  = (float*)(aggb + NR);             // (unused after fusion)
    ushort* Bt   = (ushort*)(tmp + NR);             // 6 x [256,256] bf16 W^T
    int* row_ptr = (int*)(Bt + 6 * 256 * 256);
    int* cursor  = row_ptr + (N + 1);
    int* deg     = cursor + N;
    int* incl    = deg + N;
    int* partials= incl + N;
    int* esrc    = partials + 1024;

    ushort* Bt_pool0  = Bt + 0 * 65536;
    ushort* Bt_self0  = Bt + 1 * 65536;
    ushort* Bt_neigh0 = Bt + 2 * 65536;
    ushort* Bt_pool1  = Bt + 3 * 65536;
    ushort* Bt_self1  = Bt + 4 * 65536;
    ushort* Bt_neigh1 = Bt + 5 * 65536;

    const int  gemm_blocks = ((N + 127) / 128) * 2;        // 1D swizzled grid
    const int  l2n_blocks  = (N + 127) / 128;              // fused full-row tile
    const int  q_blocks    = ((E >> 2) + 1 + 255) / 256;
    const int  node_blocks = (N + 3) / 4;
    const int  conv_blocks = (int)((NR / 4 + 255) / 256);
    const int  scan_blocks = (N + 1023) / 1024;

    // ---------------- one-time conversions ----------------
    WP6 wp;
    wp.p[0] = { W_pool0,  Bt_pool0  };
    wp.p[1] = { W_self0,  Bt_self0  };
    wp.p[2] = { W_neigh0, Bt_neigh0 };
    wp.p[3] = { W_pool1,  Bt_pool1  };
    wp.p[4] = { W_self1,  Bt_self1  };
    wp.p[5] = { W_neigh1, Bt_neigh1 };
    wtrans_kernel<<<dim3(8, 8, 6), 256, 0, stream>>>(wp);
    f2bf_kernel<<<conv_blocks, 256, 0, stream>>>(x, xb, (int)(NR / 4));

    // ---------------- CSR build ----------------
    hipMemsetAsync(deg, 0, (size_t)N * sizeof(int), stream);
    hist_kernel<<<q_blocks, 256, 0, stream>>>(dst, deg, E);
    blockscan_kernel<<<scan_blocks, 1024, 0, stream>>>(deg, incl, partials, N);
    scanp_kernel<<<1, 1024, 0, stream>>>(partials, scan_blocks);
    finalize_kernel<<<scan_blocks, 1024, 0, stream>>>(deg, incl, partials,
                                                      row_ptr, cursor, N, E);
    bucket_kernel<<<q_blocks, 256, 0, stream>>>(src, dst, cursor, esrc, E);

    // ---------------- layer 0 ----------------
    mfma_gemm_kernel<0,1,1><<<gemm_blocks, 256, 0, stream>>>(xb, Bt_pool0, nullptr, nullptr,
                                                             b_pool0, mb, N);
    agg_max_kernel<<<node_blocks, 256, 0, stream>>>(row_ptr, esrc, mb, aggb, N);
    // fused: enc = l2norm(relu(x@Wself0 + agg@Wneigh0 + b0)); xb <- bf16(enc)
    mfma_dual_l2n_kernel<<<l2n_blocks, 256, 0, stream>>>(xb, Bt_self0, aggb, Bt_neigh0,
                                                         b0, enc, xb, N);

    // ---------------- layer 1 ----------------
    mfma_gemm_kernel<0,1,1><<<gemm_blocks, 256, 0, stream>>>(xb, Bt_pool1, nullptr, nullptr,
                                                             b_pool1, mb, N);
    agg_max_kernel<<<node_blocks, 256, 0, stream>>>(row_ptr, esrc, mb, aggb, N);
    mfma_gemm_kernel<1,0,0><<<gemm_blocks, 256, 0, stream>>>(xb, Bt_self1, aggb, Bt_neigh1,
                                                             b1, h1, N);
}

// Round 15
// 349.427 us; speedup vs baseline: 1.1806x; 1.0170x over previous
//
#include <hip/hip_runtime.h>
#include <cstddef>

#define D256 256

typedef __attribute__((ext_vector_type(8))) short bf16x8;
typedef __attribute__((ext_vector_type(4))) float f32x4;

// global -> LDS direct (16B per lane, wave-uniform LDS base + lane*16)
#define GLOAD16(gptr, lptr)                                                         \
    __builtin_amdgcn_global_load_lds(                                               \
        (const __attribute__((address_space(1))) unsigned int*)(gptr),              \
        (__attribute__((address_space(3))) unsigned int*)(lptr), 16, 0, 0)

__device__ __forceinline__ ushort f2bf(float f) {
    unsigned u = __float_as_uint(f);
    return (ushort)((u + 0x7FFFu + ((u >> 16) & 1u)) >> 16);   // RNE
}
__device__ __forceinline__ ushort umax16(ushort a, ushort b) { return a > b ? a : b; }
__device__ __forceinline__ ushort4 vmax4(ushort4 a, ushort4 b) {
    return make_ushort4(umax16(a.x, b.x), umax16(a.y, b.y),
                        umax16(a.z, b.z), umax16(a.w, b.w));
}

// ---------------- MFMA GEMM: out = act( A@Bt^T (+ A2@Bt2^T) + bias ) ----------------
// 128x128 tile, 4 waves (2x2), 64x64/wave, BK=32, 16x16x32 MFMA.
// 2-phase dbuf global_load_lds staging; 1D grid + bijective XCD swizzle (m204).
// Swapped-operand mfma(bf, af): D frag = (m = lane&15, n = kg*4 + reg).
template<int DUAL, int RELU, int OUT_BF16>
__global__ __launch_bounds__(256)
void mfma_gemm_kernel(const ushort* __restrict__ A, const ushort* __restrict__ Bt,
                      const ushort* __restrict__ A2, const ushort* __restrict__ Bt2,
                      const float* __restrict__ bias, void* __restrict__ outp, int M)
{
    constexpr int TILES = DUAL ? 4 : 2;          // A,B[,A2,B2]
    constexpr int BUFSZ = TILES * 4096;          // ushorts per buffer
    __shared__ ushort smem[2 * BUFSZ];

    // bijective XCD swizzle (nwg need not be a multiple of 8)
    const int nwg  = gridDim.x;
    const int q    = nwg >> 3, r = nwg & 7;
    const int xcd  = blockIdx.x & 7, jj = blockIdx.x >> 3;
    const int wgid = (xcd < r ? xcd * (q + 1) : r * (q + 1) + (xcd - r) * q) + jj;

    const int t    = threadIdx.x;
    const int m0   = (wgid >> 1) * 128;
    const int n0   = (wgid & 1) * 128;
    const int lane = t & 63;
    const int wave = t >> 6;
    const int wr   = (wave >> 1) * 64;
    const int wc   = (wave & 1) * 64;
    const int lr   = lane & 15;
    const int kg   = lane >> 4;

    const int lrow  = lane >> 2;
    const int lch   = lane & 3;
    const int srow0 = wave * 32;

    f32x4 acc[4][4];
#pragma unroll
    for (int i = 0; i < 4; ++i)
#pragma unroll
        for (int j = 0; j < 4; ++j) acc[i][j] = (f32x4)(0.0f);

    auto STAGE = [&](int buf, int k0) {
        ushort* const base = smem + buf * BUFSZ;
#pragma unroll
        for (int i = 0; i < 2; ++i) {
            const int r2  = srow0 + i * 16;
            const int ar  = m0 + r2 + lrow;
            const int arc = ar < M ? ar : (M - 1);
            const size_t ga = (size_t)arc * D256 + k0 + lch * 8;
            const size_t gb = (size_t)(n0 + r2 + lrow) * D256 + k0 + lch * 8;
            GLOAD16(A + ga, base + r2 * 32);
            GLOAD16(Bt + gb, base + 4096 + r2 * 32);
            if (DUAL) {
                GLOAD16(A2 + ga, base + 8192 + r2 * 32);
                GLOAD16(Bt2 + gb, base + 12288 + r2 * 32);
            }
        }
    };

    STAGE(0, 0);
#pragma unroll
    for (int ks = 0; ks < 8; ++ks) {
        const int cur = ks & 1;
        __syncthreads();
        if (ks < 7) STAGE(cur ^ 1, (ks + 1) * 32);

        ushort* const base = smem + cur * BUFSZ;
        bf16x8 af[4], bf[4];
#pragma unroll
        for (int mi = 0; mi < 4; ++mi)
            af[mi] = *(const bf16x8*)&base[(wr + mi * 16 + lr) * 32 + kg * 8];
#pragma unroll
        for (int ni = 0; ni < 4; ++ni)
            bf[ni] = *(const bf16x8*)&base[4096 + (wc + ni * 16 + lr) * 32 + kg * 8];
#pragma unroll
        for (int mi = 0; mi < 4; ++mi)
#pragma unroll
            for (int ni = 0; ni < 4; ++ni)
                acc[mi][ni] = __builtin_amdgcn_mfma_f32_16x16x32_bf16(
                    bf[ni], af[mi], acc[mi][ni], 0, 0, 0);
        if (DUAL) {
            bf16x8 af2[4], bf2[4];
#pragma unroll
            for (int mi = 0; mi < 4; ++mi)
                af2[mi] = *(const bf16x8*)&base[8192 + (wr + mi * 16 + lr) * 32 + kg * 8];
#pragma unroll
            for (int ni = 0; ni < 4; ++ni)
                bf2[ni] = *(const bf16x8*)&base[12288 + (wc + ni * 16 + lr) * 32 + kg * 8];
#pragma unroll
            for (int mi = 0; mi < 4; ++mi)
#pragma unroll
                for (int ni = 0; ni < 4; ++ni)
                    acc[mi][ni] = __builtin_amdgcn_mfma_f32_16x16x32_bf16(
                        bf2[ni], af2[mi], acc[mi][ni], 0, 0, 0);
        }
    }

#pragma unroll
    for (int ni = 0; ni < 4; ++ni) {
        const int colb = n0 + wc + ni * 16 + kg * 4;
        const float4 bb = *(const float4*)(bias + colb);
#pragma unroll
        for (int mi = 0; mi < 4; ++mi) {
            const int row = m0 + wr + mi * 16 + lr;
            if (row < M) {
                const f32x4 a = acc[mi][ni];
                float4 o;
                o.x = a[0] + bb.x;
                o.y = a[1] + bb.y;
                o.z = a[2] + bb.z;
                o.w = a[3] + bb.w;
                if (RELU) {
                    o.x = fmaxf(o.x, 0.f); o.y = fmaxf(o.y, 0.f);
                    o.z = fmaxf(o.z, 0.f); o.w = fmaxf(o.w, 0.f);
                }
                if (OUT_BF16) {
                    ushort4 ob;
                    ob.x = f2bf(o.x); ob.y = f2bf(o.y);
                    ob.z = f2bf(o.z); ob.w = f2bf(o.w);
                    *(ushort4*)((ushort*)outp + (size_t)row * D256 + colb) = ob;
                } else {
                    *(float4*)((float*)outp + (size_t)row * D256 + colb) = o;
                }
            }
        }
    }
}

// ------ fused dual GEMM + relu + row-l2norm: enc_f = l2n(relu(A@Bt^T + A2@Bt2^T + b)),
// ------ enc_b = bf16(enc_f). Tile 128 rows x FULL 256 cols; block owns whole rows.
__global__ __launch_bounds__(256)
void mfma_dual_l2n_kernel(const ushort* A, const ushort* __restrict__ Bt,
                          const ushort* __restrict__ A2, const ushort* __restrict__ Bt2,
                          const float* __restrict__ bias,
                          float* __restrict__ enc_f, ushort* enc_b, int M)
{
    __shared__ ushort smem[24576];        // A:0 | B:4096 | A2:12288 | B2:16384
    __shared__ float  ssq_lds[128][2];

    const int t    = threadIdx.x;
    const int m0   = blockIdx.x * 128;
    const int lane = t & 63;
    const int wave = t >> 6;
    const int wr   = (wave >> 1) * 64;    // rows 0-63 / 64-127
    const int wc   = (wave & 1) * 128;    // cols 0-127 / 128-255
    const int lr   = lane & 15;
    const int kg   = lane >> 4;
    const int lrow = lane >> 2;
    const int lch  = lane & 3;

    f32x4 acc[4][8];
#pragma unroll
    for (int i = 0; i < 4; ++i)
#pragma unroll
        for (int j = 0; j < 8; ++j) acc[i][j] = (f32x4)(0.0f);

    for (int ks = 0; ks < 8; ++ks) {
        const int k0 = ks * 32;
        __syncthreads();
#pragma unroll
        for (int i = 0; i < 2; ++i) {
            const int r2  = wave * 32 + i * 16;
            const int ar  = m0 + r2 + lrow;
            const int arc = ar < M ? ar : (M - 1);
            const size_t ga = (size_t)arc * D256 + k0 + lch * 8;
            GLOAD16(A + ga, smem + r2 * 32);
            GLOAD16(A2 + ga, smem + 12288 + r2 * 32);
        }
#pragma unroll
        for (int i = 0; i < 4; ++i) {
            const int r2 = wave * 64 + i * 16;
            const size_t gb = (size_t)(r2 + lrow) * D256 + k0 + lch * 8;
            GLOAD16(Bt + gb, smem + 4096 + r2 * 32);
            GLOAD16(Bt2 + gb, smem + 16384 + r2 * 32);
        }
        __syncthreads();

        bf16x8 af[4];
#pragma unroll
        for (int mi = 0; mi < 4; ++mi)
            af[mi] = *(const bf16x8*)&smem[(wr + mi * 16 + lr) * 32 + kg * 8];
#pragma unroll
        for (int ni = 0; ni < 8; ++ni) {
            const bf16x8 b = *(const bf16x8*)&smem[4096 + (wc + ni * 16 + lr) * 32 + kg * 8];
#pragma unroll
            for (int mi = 0; mi < 4; ++mi)
                acc[mi][ni] = __builtin_amdgcn_mfma_f32_16x16x32_bf16(
                    b, af[mi], acc[mi][ni], 0, 0, 0);
        }
#pragma unroll
        for (int mi = 0; mi < 4; ++mi)
            af[mi] = *(const bf16x8*)&smem[12288 + (wr + mi * 16 + lr) * 32 + kg * 8];
#pragma unroll
        for (int ni = 0; ni < 8; ++ni) {
            const bf16x8 b = *(const bf16x8*)&smem[16384 + (wc + ni * 16 + lr) * 32 + kg * 8];
#pragma unroll
            for (int mi = 0; mi < 4; ++mi)
                acc[mi][ni] = __builtin_amdgcn_mfma_f32_16x16x32_bf16(
                    b, af[mi], acc[mi][ni], 0, 0, 0);
        }
    }

    float ssq[4] = {0.f, 0.f, 0.f, 0.f};
#pragma unroll
    for (int mi = 0; mi < 4; ++mi)
#pragma unroll
        for (int ni = 0; ni < 8; ++ni) {
            const int colb = wc + ni * 16 + kg * 4;
            const float4 bb = *(const float4*)(bias + colb);
            f32x4 a = acc[mi][ni];
            a[0] = fmaxf(a[0] + bb.x, 0.f);
            a[1] = fmaxf(a[1] + bb.y, 0.f);
            a[2] = fmaxf(a[2] + bb.z, 0.f);
            a[3] = fmaxf(a[3] + bb.w, 0.f);
            acc[mi][ni] = a;
            ssq[mi] += a[0] * a[0] + a[1] * a[1] + a[2] * a[2] + a[3] * a[3];
        }
#pragma unroll
    for (int mi = 0; mi < 4; ++mi) {
        ssq[mi] += __shfl_xor(ssq[mi], 16);
        ssq[mi] += __shfl_xor(ssq[mi], 32);
    }
    __syncthreads();
    if (kg == 0) {
#pragma unroll
        for (int mi = 0; mi < 4; ++mi)
            ssq_lds[wr + mi * 16 + lr][wave & 1] = ssq[mi];
    }
    __syncthreads();
#pragma unroll
    for (int mi = 0; mi < 4; ++mi) {
        const int rrow = wr + mi * 16 + lr;
        const int row  = m0 + rrow;
        const float tot = ssq_lds[rrow][0] + ssq_lds[rrow][1];
        const float inv = 1.0f / fmaxf(sqrtf(tot), 1e-12f);
        if (row < M) {
#pragma unroll
            for (int ni = 0; ni < 8; ++ni) {
                const int colb = wc + ni * 16 + kg * 4;
                const f32x4 a = acc[mi][ni];
                float4 o;
                o.x = a[0] * inv; o.y = a[1] * inv;
                o.z = a[2] * inv; o.w = a[3] * inv;
                *(float4*)(enc_f + (size_t)row * D256 + colb) = o;
                ushort4 ob;
                ob.x = f2bf(o.x); ob.y = f2bf(o.y);
                ob.z = f2bf(o.z); ob.w = f2bf(o.w);
                *(ushort4*)(enc_b + (size_t)row * D256 + colb) = ob;
            }
        }
    }
}

// ---------------- fp32 -> bf16 convert ----------------
__global__ __launch_bounds__(256)
void f2bf_kernel(const float* __restrict__ in, ushort* __restrict__ out, int n4)
{
    const int i = blockIdx.x * 256 + threadIdx.x;
    if (i >= n4) return;
    const float4 v = ((const float4*)in)[i];
    ushort4 o;
    o.x = f2bf(v.x); o.y = f2bf(v.y); o.z = f2bf(v.z); o.w = f2bf(v.w);
    ((ushort4*)out)[i] = o;
}

// ---------------- weight transpose+convert: Bt[n][k] = bf16(W[k][n]) ----------------
struct WP  { const float* w; ushort* o; };
struct WP6 { WP p[6]; };
__global__ __launch_bounds__(256)
void wtrans_kernel(WP6 ps)
{
    const float* __restrict__ W = ps.p[blockIdx.z].w;
    ushort* __restrict__ O      = ps.p[blockIdx.z].o;
    __shared__ float sm[32][33];
    const int tx = threadIdx.x & 31, ty = threadIdx.x >> 5;
    const int k0 = blockIdx.x * 32, n0 = blockIdx.y * 32;
#pragma unroll
    for (int i = 0; i < 4; ++i)
        sm[ty + i * 8][tx] = W[(size_t)(k0 + ty + i * 8) * D256 + n0 + tx];
    __syncthreads();
#pragma unroll
    for (int i = 0; i < 4; ++i)
        O[(size_t)(n0 + ty + i * 8) * D256 + k0 + tx] = f2bf(sm[tx][ty + i * 8]);
}

// ---------------- CSR build ----------------
__global__ __launch_bounds__(256)
void hist_kernel(const int* __restrict__ dst, int* __restrict__ deg, int E)
{
    const int nq = E >> 2;
    const int i  = blockIdx.x * 256 + threadIdx.x;
    if (i < nq) {
        const int4 d = ((const int4*)dst)[i];
        atomicAdd(&deg[d.x], 1);
        atomicAdd(&deg[d.y], 1);
        atomicAdd(&deg[d.z], 1);
        atomicAdd(&deg[d.w], 1);
    } else if (i == nq) {
        for (int e = nq * 4; e < E; ++e) atomicAdd(&deg[dst[e]], 1);
    }
}

__global__ __launch_bounds__(1024)
void blockscan_kernel(const int* __restrict__ deg, int* __restrict__ incl,
                      int* __restrict__ partials, int N)
{
    __shared__ int wt[16];
    const int i    = blockIdx.x * 1024 + threadIdx.x;
    const int lane = threadIdx.x & 63;
    const int wv   = threadIdx.x >> 6;
    const int v    = (i < N) ? deg[i] : 0;
    int s = v;
#pragma unroll
    for (int o = 1; o < 64; o <<= 1) {
        const int t = __shfl_up(s, o);
        if (lane >= o) s += t;
    }
    if (lane == 63) wt[wv] = s;
    __syncthreads();
    if (wv == 0 && lane < 16) {
        const int w = wt[lane];
        int ws = w;
#pragma unroll
        for (int o = 1; o < 16; o <<= 1) {
            const int t = __shfl_up(ws, o);
            if (lane >= o) ws += t;
        }
        wt[lane] = ws - w;
    }
    __syncthreads();
    s += wt[wv];
    if (i < N) incl[i] = s;
    if (threadIdx.x == 1023) partials[blockIdx.x] = s;
}

__global__ __launch_bounds__(1024)
void scanp_kernel(int* __restrict__ partials, int nb)
{
    __shared__ int sm[1024];
    const int v = (threadIdx.x < (unsigned)nb) ? partials[threadIdx.x] : 0;
    sm[threadIdx.x] = v;
    __syncthreads();
#pragma unroll
    for (int off = 1; off < 1024; off <<= 1) {
        const int t = (threadIdx.x >= (unsigned)off) ? sm[threadIdx.x - off] : 0;
        __syncthreads();
        sm[threadIdx.x] += t;
        __syncthreads();
    }
    if (threadIdx.x < (unsigned)nb) partials[threadIdx.x] = sm[threadIdx.x] - v;
}

__global__ __launch_bounds__(1024)
void finalize_kernel(const int* __restrict__ deg, const int* __restrict__ incl,
                     const int* __restrict__ partials, int* __restrict__ row_ptr,
                     int* __restrict__ cursor, int N, int E)
{
    const int i = blockIdx.x * 1024 + threadIdx.x;
    if (i < N) {
        const int ex = partials[blockIdx.x] + incl[i] - deg[i];
        row_ptr[i] = ex;
        cursor[i]  = ex;
    }
    if (i == 0) row_ptr[N] = E;
}

// dst-range-partitioned bucket scatter: group = blockIdx.x & 7 (consecutive
// blockIdx round-robin across the 8 XCDs -> group g's blocks land on XCD g).
// Each group scans ALL edges (coalesced int4, 8x re-read = ~51MB streaming)
// but scatters only dst in [lo,hi): every esrc line is written by ONE XCD,
// active esrc region/XCD = 400KB (L2-resident) -> no cross-XCD line ping-pong.
__global__ __launch_bounds__(256)
void bucket_kernel(const int* __restrict__ src, const int* __restrict__ dst,
                   int* __restrict__ cursor, int* __restrict__ esrc, int E, int N)
{
    const int group = blockIdx.x & 7;
    const int gblk  = blockIdx.x >> 3;
    const int nblk  = gridDim.x >> 3;
    const int lo = (int)(((long)N * group) >> 3);
    const int hi = (int)(((long)N * (group + 1)) >> 3);
    const int nq = E >> 2;

    for (int i = gblk * 256 + threadIdx.x; i < nq; i += nblk * 256) {
        const int4 d = ((const int4*)dst)[i];
        const int4 s = ((const int4*)src)[i];
        if (d.x >= lo && d.x < hi) esrc[atomicAdd(&cursor[d.x], 1)] = s.x;
        if (d.y >= lo && d.y < hi) esrc[atomicAdd(&cursor[d.y], 1)] = s.y;
        if (d.z >= lo && d.z < hi) esrc[atomicAdd(&cursor[d.z], 1)] = s.z;
        if (d.w >= lo && d.w < hi) esrc[atomicAdd(&cursor[d.w], 1)] = s.w;
    }
    if (gblk == 0 && threadIdx.x == 0) {
        for (int e = nq * 4; e < E; ++e) {
            const int d = dst[e];
            if (d >= lo && d < hi) esrc[atomicAdd(&cursor[d], 1)] = src[e];
        }
    }
}

// ---------------- node-parallel segment max over bf16 rows ----------------
__global__ __launch_bounds__(256)
void agg_max_kernel(const int* __restrict__ row_ptr, const int* __restrict__ esrc,
                    const ushort* __restrict__ m, ushort* __restrict__ agg, int N)
{
    const int wid  = (int)(((size_t)blockIdx.x * 256 + threadIdx.x) >> 6);
    const int lane = threadIdx.x & 63;
    if (wid >= N) return;
    const int beg = row_ptr[wid];
    const int end = row_ptr[wid + 1];
    const size_t off = (size_t)(lane * 4);

    ushort4 a0 = make_ushort4(0, 0, 0, 0);
    ushort4 a1 = a0, a2 = a0, a3 = a0;
    int e = beg;
    for (; e + 8 <= end; e += 8) {
        int s[8];
#pragma unroll
        for (int q = 0; q < 8; ++q) s[q] = esrc[e + q];
        ushort4 v[8];
#pragma unroll
        for (int q = 0; q < 8; ++q)
            v[q] = *(const ushort4*)(m + (size_t)s[q] * D256 + off);
        a0 = vmax4(a0, vmax4(v[0], v[4]));
        a1 = vmax4(a1, vmax4(v[1], v[5]));
        a2 = vmax4(a2, vmax4(v[2], v[6]));
        a3 = vmax4(a3, vmax4(v[3], v[7]));
    }
    for (; e + 2 <= end; e += 2) {
        const int s0 = esrc[e];
        const int s1 = esrc[e + 1];
        const ushort4 v0 = *(const ushort4*)(m + (size_t)s0 * D256 + off);
        const ushort4 v1 = *(const ushort4*)(m + (size_t)s1 * D256 + off);
        a0 = vmax4(a0, v0);
        a1 = vmax4(a1, v1);
    }
    if (e < end) {
        const ushort4 v0 = *(const ushort4*)(m + (size_t)esrc[e] * D256 + off);
        a2 = vmax4(a2, v0);
    }
    const ushort4 r = vmax4(vmax4(a0, a1), vmax4(a2, a3));
    *(ushort4*)(agg + (size_t)wid * D256 + off) = r;
}

extern "C" void kernel_launch(void* const* d_in, const int* in_sizes, int n_in,
                              void* d_out, int out_size, void* d_ws, size_t ws_size,
                              hipStream_t stream)
{
    const float* x        = (const float*)d_in[0];
    const int*   src      = (const int*)  d_in[1];
    const int*   dst      = (const int*)  d_in[2];
    const float* W_pool0  = (const float*)d_in[3];
    const float* b_pool0  = (const float*)d_in[4];
    const float* W_self0  = (const float*)d_in[5];
    const float* W_neigh0 = (const float*)d_in[6];
    const float* b0       = (const float*)d_in[7];
    const float* W_pool1  = (const float*)d_in[8];
    const float* b_pool1  = (const float*)d_in[9];
    const float* W_self1  = (const float*)d_in[10];
    const float* W_neigh1 = (const float*)d_in[11];
    const float* b1       = (const float*)d_in[12];

    const int N = in_sizes[0] / D256;
    const int E = in_sizes[1];
    const size_t NR = (size_t)N * D256;

    float* h1  = (float*)d_out;                     // [N,256] layer-1 out (fp32)
    float* enc = (float*)d_out + NR;                // [N,256] enc_feat_input (fp32)

    ushort* xb   = (ushort*)d_ws;                   // bf16 A (x for L0, enc for L1)
    ushort* mb   = xb + NR;                         // bf16 pool msgs
    ushort* aggb = mb + NR;                         // bf16 aggregated
    float*  tmp  = (float*)(aggb + NR);             // (unused after fusion)
    ushort* Bt   = (ushort*)(tmp + NR);             // 6 x [256,256] bf16 W^T
    int* row_ptr = (int*)(Bt + 6 * 256 * 256);
    int* cursor  = row_ptr + (N + 1);
    int* deg     = cursor + N;
    int* incl    = deg + N;
    int* partials= incl + N;
    int* esrc    = partials + 1024;

    ushort* Bt_pool0  = Bt + 0 * 65536;
    ushort* Bt_self0  = Bt + 1 * 65536;
    ushort* Bt_neigh0 = Bt + 2 * 65536;
    ushort* Bt_pool1  = Bt + 3 * 65536;
    ushort* Bt_self1  = Bt + 4 * 65536;
    ushort* Bt_neigh1 = Bt + 5 * 65536;

    const int  gemm_blocks = ((N + 127) / 128) * 2;        // 1D swizzled grid
    const int  l2n_blocks  = (N + 127) / 128;              // fused full-row tile
    const int  q_blocks    = ((E >> 2) + 1 + 255) / 256;
    const int  bkt_blocks  = 2048;                         // 8 groups x 256
    const int  node_blocks = (N + 3) / 4;
    const int  conv_blocks = (int)((NR / 4 + 255) / 256);
    const int  scan_blocks = (N + 1023) / 1024;

    // ---------------- one-time conversions ----------------
    WP6 wp;
    wp.p[0] = { W_pool0,  Bt_pool0  };
    wp.p[1] = { W_self0,  Bt_self0  };
    wp.p[2] = { W_neigh0, Bt_neigh0 };
    wp.p[3] = { W_pool1,  Bt_pool1  };
    wp.p[4] = { W_self1,  Bt_self1  };
    wp.p[5] = { W_neigh1, Bt_neigh1 };
    wtrans_kernel<<<dim3(8, 8, 6), 256, 0, stream>>>(wp);
    f2bf_kernel<<<conv_blocks, 256, 0, stream>>>(x, xb, (int)(NR / 4));

    // ---------------- CSR build ----------------
    hipMemsetAsync(deg, 0, (size_t)N * sizeof(int), stream);
    hist_kernel<<<q_blocks, 256, 0, stream>>>(dst, deg, E);
    blockscan_kernel<<<scan_blocks, 1024, 0, stream>>>(deg, incl, partials, N);
    scanp_kernel<<<1, 1024, 0, stream>>>(partials, scan_blocks);
    finalize_kernel<<<scan_blocks, 1024, 0, stream>>>(deg, incl, partials,
                                                      row_ptr, cursor, N, E);
    bucket_kernel<<<bkt_blocks, 256, 0, stream>>>(src, dst, cursor, esrc, E, N);

    // ---------------- layer 0 ----------------
    mfma_gemm_kernel<0,1,1><<<gemm_blocks, 256, 0, stream>>>(xb, Bt_pool0, nullptr, nullptr,
                                                             b_pool0, mb, N);
    agg_max_kernel<<<node_blocks, 256, 0, stream>>>(row_ptr, esrc, mb, aggb, N);
    // fused: enc = l2norm(relu(x@Wself0 + agg@Wneigh0 + b0)); xb <- bf16(enc)
    mfma_dual_l2n_kernel<<<l2n_blocks, 256, 0, stream>>>(xb, Bt_self0, aggb, Bt_neigh0,
                                                         b0, enc, xb, N);

    // ---------------- layer 1 ----------------
    mfma_gemm_kernel<0,1,1><<<gemm_blocks, 256, 0, stream>>>(xb, Bt_pool1, nullptr, nullptr,
                                                             b_pool1, mb, N);
    agg_max_kernel<<<node_blocks, 256, 0, stream>>>(row_ptr, esrc, mb, aggb, N);
    mfma_gemm_kernel<1,0,0><<<gemm_blocks, 256, 0, stream>>>(xb, Bt_self1, aggb, Bt_neigh1,
                                                             b1, h1, N);
}

// Round 16
// 342.464 us; speedup vs baseline: 1.2046x; 1.0203x over previous
//
#include <hip/hip_runtime.h>
#include <cstddef>

#define D256 256

typedef __attribute__((ext_vector_type(8))) short bf16x8;
typedef __attribute__((ext_vector_type(4))) float f32x4;

// global -> LDS direct (16B per lane, wave-uniform LDS base + lane*16)
#define GLOAD16(gptr, lptr)                                                         \
    __builtin_amdgcn_global_load_lds(                                               \
        (const __attribute__((address_space(1))) unsigned int*)(gptr),              \
        (__attribute__((address_space(3))) unsigned int*)(lptr), 16, 0, 0)

__device__ __forceinline__ ushort f2bf(float f) {
    unsigned u = __float_as_uint(f);
    return (ushort)((u + 0x7FFFu + ((u >> 16) & 1u)) >> 16);   // RNE
}
__device__ __forceinline__ ushort umax16(ushort a, ushort b) { return a > b ? a : b; }
__device__ __forceinline__ ushort4 vmax4(ushort4 a, ushort4 b) {
    return make_ushort4(umax16(a.x, b.x), umax16(a.y, b.y),
                        umax16(a.z, b.z), umax16(a.w, b.w));
}

// ---------------- MFMA GEMM: out = act( A@Bt^T (+ A2@Bt2^T) + bias ) ----------------
// 128x128 tile, 4 waves (2x2), 64x64/wave, BK=32, 16x16x32 MFMA.
// 2-phase dbuf global_load_lds staging; 1D grid + bijective XCD swizzle (m204).
// Swapped-operand mfma(bf, af): D frag = (m = lane&15, n = kg*4 + reg).
template<int DUAL, int RELU, int OUT_BF16>
__global__ __launch_bounds__(256)
void mfma_gemm_kernel(const ushort* __restrict__ A, const ushort* __restrict__ Bt,
                      const ushort* __restrict__ A2, const ushort* __restrict__ Bt2,
                      const float* __restrict__ bias, void* __restrict__ outp, int M)
{
    constexpr int TILES = DUAL ? 4 : 2;          // A,B[,A2,B2]
    constexpr int BUFSZ = TILES * 4096;          // ushorts per buffer
    __shared__ ushort smem[2 * BUFSZ];

    // bijective XCD swizzle (nwg need not be a multiple of 8)
    const int nwg  = gridDim.x;
    const int q    = nwg >> 3, r = nwg & 7;
    const int xcd  = blockIdx.x & 7, jj = blockIdx.x >> 3;
    const int wgid = (xcd < r ? xcd * (q + 1) : r * (q + 1) + (xcd - r) * q) + jj;

    const int t    = threadIdx.x;
    const int m0   = (wgid >> 1) * 128;
    const int n0   = (wgid & 1) * 128;
    const int lane = t & 63;
    const int wave = t >> 6;
    const int wr   = (wave >> 1) * 64;
    const int wc   = (wave & 1) * 64;
    const int lr   = lane & 15;
    const int kg   = lane >> 4;

    const int lrow  = lane >> 2;
    const int lch   = lane & 3;
    const int srow0 = wave * 32;

    f32x4 acc[4][4];
#pragma unroll
    for (int i = 0; i < 4; ++i)
#pragma unroll
        for (int j = 0; j < 4; ++j) acc[i][j] = (f32x4)(0.0f);

    auto STAGE = [&](int buf, int k0) {
        ushort* const base = smem + buf * BUFSZ;
#pragma unroll
        for (int i = 0; i < 2; ++i) {
            const int r2  = srow0 + i * 16;
            const int ar  = m0 + r2 + lrow;
            const int arc = ar < M ? ar : (M - 1);
            const size_t ga = (size_t)arc * D256 + k0 + lch * 8;
            const size_t gb = (size_t)(n0 + r2 + lrow) * D256 + k0 + lch * 8;
            GLOAD16(A + ga, base + r2 * 32);
            GLOAD16(Bt + gb, base + 4096 + r2 * 32);
            if (DUAL) {
                GLOAD16(A2 + ga, base + 8192 + r2 * 32);
                GLOAD16(Bt2 + gb, base + 12288 + r2 * 32);
            }
        }
    };

    STAGE(0, 0);
#pragma unroll
    for (int ks = 0; ks < 8; ++ks) {
        const int cur = ks & 1;
        __syncthreads();
        if (ks < 7) STAGE(cur ^ 1, (ks + 1) * 32);

        ushort* const base = smem + cur * BUFSZ;
        bf16x8 af[4], bf[4];
#pragma unroll
        for (int mi = 0; mi < 4; ++mi)
            af[mi] = *(const bf16x8*)&base[(wr + mi * 16 + lr) * 32 + kg * 8];
#pragma unroll
        for (int ni = 0; ni < 4; ++ni)
            bf[ni] = *(const bf16x8*)&base[4096 + (wc + ni * 16 + lr) * 32 + kg * 8];
#pragma unroll
        for (int mi = 0; mi < 4; ++mi)
#pragma unroll
            for (int ni = 0; ni < 4; ++ni)
                acc[mi][ni] = __builtin_amdgcn_mfma_f32_16x16x32_bf16(
                    bf[ni], af[mi], acc[mi][ni], 0, 0, 0);
        if (DUAL) {
            bf16x8 af2[4], bf2[4];
#pragma unroll
            for (int mi = 0; mi < 4; ++mi)
                af2[mi] = *(const bf16x8*)&base[8192 + (wr + mi * 16 + lr) * 32 + kg * 8];
#pragma unroll
            for (int ni = 0; ni < 4; ++ni)
                bf2[ni] = *(const bf16x8*)&base[12288 + (wc + ni * 16 + lr) * 32 + kg * 8];
#pragma unroll
            for (int mi = 0; mi < 4; ++mi)
#pragma unroll
                for (int ni = 0; ni < 4; ++ni)
                    acc[mi][ni] = __builtin_amdgcn_mfma_f32_16x16x32_bf16(
                        bf2[ni], af2[mi], acc[mi][ni], 0, 0, 0);
        }
    }

#pragma unroll
    for (int ni = 0; ni < 4; ++ni) {
        const int colb = n0 + wc + ni * 16 + kg * 4;
        const float4 bb = *(const float4*)(bias + colb);
#pragma unroll
        for (int mi = 0; mi < 4; ++mi) {
            const int row = m0 + wr + mi * 16 + lr;
            if (row < M) {
                const f32x4 a = acc[mi][ni];
                float4 o;
                o.x = a[0] + bb.x;
                o.y = a[1] + bb.y;
                o.z = a[2] + bb.z;
                o.w = a[3] + bb.w;
                if (RELU) {
                    o.x = fmaxf(o.x, 0.f); o.y = fmaxf(o.y, 0.f);
                    o.z = fmaxf(o.z, 0.f); o.w = fmaxf(o.w, 0.f);
                }
                if (OUT_BF16) {
                    ushort4 ob;
                    ob.x = f2bf(o.x); ob.y = f2bf(o.y);
                    ob.z = f2bf(o.z); ob.w = f2bf(o.w);
                    *(ushort4*)((ushort*)outp + (size_t)row * D256 + colb) = ob;
                } else {
                    *(float4*)((float*)outp + (size_t)row * D256 + colb) = o;
                }
            }
        }
    }
}

// ------ fused dual GEMM + relu + row-l2norm: enc_f = l2n(relu(A@Bt^T + A2@Bt2^T + b)),
// ------ enc_b = bf16(enc_f). Tile 64 rows x FULL 256 cols (block owns whole rows ->
// ------ norm block-local; enc_b aliases A but only the block's own disjoint rows are
// ------ written, after the K-loop). 4 waves: (wave>>1)=row-half of 32, (wave&1)=col-half
// ------ of 128; acc[2][8]. 40KB LDS -> 782 blocks, ~3 blocks/CU (vs 1.5 at 128-row).
__global__ __launch_bounds__(256)
void mfma_dual_l2n_kernel(const ushort* A, const ushort* __restrict__ Bt,
                          const ushort* __restrict__ A2, const ushort* __restrict__ Bt2,
                          const float* __restrict__ bias,
                          float* __restrict__ enc_f, ushort* enc_b, int M)
{
    __shared__ ushort smem[20480];        // A:0 | A2:2048 | B:4096 | B2:12288
    __shared__ float  ssq_lds[64][2];

    const int t    = threadIdx.x;
    const int m0   = blockIdx.x * 64;
    const int lane = t & 63;
    const int wave = t >> 6;
    const int wr   = (wave >> 1) * 32;    // rows 0-31 / 32-63
    const int wc   = (wave & 1) * 128;    // cols 0-127 / 128-255
    const int lr   = lane & 15;
    const int kg   = lane >> 4;
    const int lrow = lane >> 2;
    const int lch  = lane & 3;

    f32x4 acc[2][8];
#pragma unroll
    for (int i = 0; i < 2; ++i)
#pragma unroll
        for (int j = 0; j < 8; ++j) acc[i][j] = (f32x4)(0.0f);

    for (int ks = 0; ks < 8; ++ks) {
        const int k0 = ks * 32;
        __syncthreads();
        // A/A2: 1 inst each per wave (16 rows); B/B2: 4 insts each per wave
        {
            const int r2  = wave * 16;
            const int ar  = m0 + r2 + lrow;
            const int arc = ar < M ? ar : (M - 1);
            const size_t ga = (size_t)arc * D256 + k0 + lch * 8;
            GLOAD16(A + ga, smem + r2 * 32);
            GLOAD16(A2 + ga, smem + 2048 + r2 * 32);
        }
#pragma unroll
        for (int i = 0; i < 4; ++i) {
            const int r2 = wave * 64 + i * 16;
            const size_t gb = (size_t)(r2 + lrow) * D256 + k0 + lch * 8;
            GLOAD16(Bt + gb, smem + 4096 + r2 * 32);
            GLOAD16(Bt2 + gb, smem + 12288 + r2 * 32);
        }
        __syncthreads();

        bf16x8 af[2];
#pragma unroll
        for (int mi = 0; mi < 2; ++mi)
            af[mi] = *(const bf16x8*)&smem[(wr + mi * 16 + lr) * 32 + kg * 8];
#pragma unroll
        for (int ni = 0; ni < 8; ++ni) {
            const bf16x8 b = *(const bf16x8*)&smem[4096 + (wc + ni * 16 + lr) * 32 + kg * 8];
#pragma unroll
            for (int mi = 0; mi < 2; ++mi)
                acc[mi][ni] = __builtin_amdgcn_mfma_f32_16x16x32_bf16(
                    b, af[mi], acc[mi][ni], 0, 0, 0);
        }
#pragma unroll
        for (int mi = 0; mi < 2; ++mi)
            af[mi] = *(const bf16x8*)&smem[2048 + (wr + mi * 16 + lr) * 32 + kg * 8];
#pragma unroll
        for (int ni = 0; ni < 8; ++ni) {
            const bf16x8 b = *(const bf16x8*)&smem[12288 + (wc + ni * 16 + lr) * 32 + kg * 8];
#pragma unroll
            for (int mi = 0; mi < 2; ++mi)
                acc[mi][ni] = __builtin_amdgcn_mfma_f32_16x16x32_bf16(
                    b, af[mi], acc[mi][ni], 0, 0, 0);
        }
    }

    // epilogue: bias + relu, per-row ssq, cross-kg + cross-colhalf reduce, scale, store
    float ssq[2] = {0.f, 0.f};
#pragma unroll
    for (int mi = 0; mi < 2; ++mi)
#pragma unroll
        for (int ni = 0; ni < 8; ++ni) {
            const int colb = wc + ni * 16 + kg * 4;
            const float4 bb = *(const float4*)(bias + colb);
            f32x4 a = acc[mi][ni];
            a[0] = fmaxf(a[0] + bb.x, 0.f);
            a[1] = fmaxf(a[1] + bb.y, 0.f);
            a[2] = fmaxf(a[2] + bb.z, 0.f);
            a[3] = fmaxf(a[3] + bb.w, 0.f);
            acc[mi][ni] = a;
            ssq[mi] += a[0] * a[0] + a[1] * a[1] + a[2] * a[2] + a[3] * a[3];
        }
#pragma unroll
    for (int mi = 0; mi < 2; ++mi) {
        ssq[mi] += __shfl_xor(ssq[mi], 16);
        ssq[mi] += __shfl_xor(ssq[mi], 32);
    }
    __syncthreads();
    if (kg == 0) {
#pragma unroll
        for (int mi = 0; mi < 2; ++mi)
            ssq_lds[wr + mi * 16 + lr][wave & 1] = ssq[mi];
    }
    __syncthreads();
#pragma unroll
    for (int mi = 0; mi < 2; ++mi) {
        const int rrow = wr + mi * 16 + lr;
        const int row  = m0 + rrow;
        const float tot = ssq_lds[rrow][0] + ssq_lds[rrow][1];
        const float inv = 1.0f / fmaxf(sqrtf(tot), 1e-12f);
        if (row < M) {
#pragma unroll
            for (int ni = 0; ni < 8; ++ni) {
                const int colb = wc + ni * 16 + kg * 4;
                const f32x4 a = acc[mi][ni];
                float4 o;
                o.x = a[0] * inv; o.y = a[1] * inv;
                o.z = a[2] * inv; o.w = a[3] * inv;
                *(float4*)(enc_f + (size_t)row * D256 + colb) = o;
                ushort4 ob;
                ob.x = f2bf(o.x); ob.y = f2bf(o.y);
                ob.z = f2bf(o.z); ob.w = f2bf(o.w);
                *(ushort4*)(enc_b + (size_t)row * D256 + colb) = ob;
            }
        }
    }
}

// ---------------- fp32 -> bf16 convert ----------------
__global__ __launch_bounds__(256)
void f2bf_kernel(const float* __restrict__ in, ushort* __restrict__ out, int n4)
{
    const int i = blockIdx.x * 256 + threadIdx.x;
    if (i >= n4) return;
    const float4 v = ((const float4*)in)[i];
    ushort4 o;
    o.x = f2bf(v.x); o.y = f2bf(v.y); o.z = f2bf(v.z); o.w = f2bf(v.w);
    ((ushort4*)out)[i] = o;
}

// ---------------- weight transpose+convert: Bt[n][k] = bf16(W[k][n]) ----------------
struct WP  { const float* w; ushort* o; };
struct WP6 { WP p[6]; };
__global__ __launch_bounds__(256)
void wtrans_kernel(WP6 ps)
{
    const float* __restrict__ W = ps.p[blockIdx.z].w;
    ushort* __restrict__ O      = ps.p[blockIdx.z].o;
    __shared__ float sm[32][33];
    const int tx = threadIdx.x & 31, ty = threadIdx.x >> 5;
    const int k0 = blockIdx.x * 32, n0 = blockIdx.y * 32;
#pragma unroll
    for (int i = 0; i < 4; ++i)
        sm[ty + i * 8][tx] = W[(size_t)(k0 + ty + i * 8) * D256 + n0 + tx];
    __syncthreads();
#pragma unroll
    for (int i = 0; i < 4; ++i)
        O[(size_t)(n0 + ty + i * 8) * D256 + k0 + tx] = f2bf(sm[tx][ty + i * 8]);
}

// ---------------- CSR build ----------------
__global__ __launch_bounds__(256)
void hist_kernel(const int* __restrict__ dst, int* __restrict__ deg, int E)
{
    const int nq = E >> 2;
    const int i  = blockIdx.x * 256 + threadIdx.x;
    if (i < nq) {
        const int4 d = ((const int4*)dst)[i];
        atomicAdd(&deg[d.x], 1);
        atomicAdd(&deg[d.y], 1);
        atomicAdd(&deg[d.z], 1);
        atomicAdd(&deg[d.w], 1);
    } else if (i == nq) {
        for (int e = nq * 4; e < E; ++e) atomicAdd(&deg[dst[e]], 1);
    }
}

__global__ __launch_bounds__(1024)
void blockscan_kernel(const int* __restrict__ deg, int* __restrict__ incl,
                      int* __restrict__ partials, int N)
{
    __shared__ int wt[16];
    const int i    = blockIdx.x * 1024 + threadIdx.x;
    const int lane = threadIdx.x & 63;
    const int wv   = threadIdx.x >> 6;
    const int v    = (i < N) ? deg[i] : 0;
    int s = v;
#pragma unroll
    for (int o = 1; o < 64; o <<= 1) {
        const int t = __shfl_up(s, o);
        if (lane >= o) s += t;
    }
    if (lane == 63) wt[wv] = s;
    __syncthreads();
    if (wv == 0 && lane < 16) {
        const int w = wt[lane];
        int ws = w;
#pragma unroll
        for (int o = 1; o < 16; o <<= 1) {
            const int t = __shfl_up(ws, o);
            if (lane >= o) ws += t;
        }
        wt[lane] = ws - w;
    }
    __syncthreads();
    s += wt[wv];
    if (i < N) incl[i] = s;
    if (threadIdx.x == 1023) partials[blockIdx.x] = s;
}

__global__ __launch_bounds__(1024)
void scanp_kernel(int* __restrict__ partials, int nb)
{
    __shared__ int sm[1024];
    const int v = (threadIdx.x < (unsigned)nb) ? partials[threadIdx.x] : 0;
    sm[threadIdx.x] = v;
    __syncthreads();
#pragma unroll
    for (int off = 1; off < 1024; off <<= 1) {
        const int t = (threadIdx.x >= (unsigned)off) ? sm[threadIdx.x - off] : 0;
        __syncthreads();
        sm[threadIdx.x] += t;
        __syncthreads();
    }
    if (threadIdx.x < (unsigned)nb) partials[threadIdx.x] = sm[threadIdx.x] - v;
}

__global__ __launch_bounds__(1024)
void finalize_kernel(const int* __restrict__ deg, const int* __restrict__ incl,
                     const int* __restrict__ partials, int* __restrict__ row_ptr,
                     int* __restrict__ cursor, int N, int E)
{
    const int i = blockIdx.x * 1024 + threadIdx.x;
    if (i < N) {
        const int ex = partials[blockIdx.x] + incl[i] - deg[i];
        row_ptr[i] = ex;
        cursor[i]  = ex;
    }
    if (i == 0) row_ptr[N] = E;
}

// dst-range-partitioned bucket scatter (one XCD owns each esrc range)
__global__ __launch_bounds__(256)
void bucket_kernel(const int* __restrict__ src, const int* __restrict__ dst,
                   int* __restrict__ cursor, int* __restrict__ esrc, int E, int N)
{
    const int group = blockIdx.x & 7;
    const int gblk  = blockIdx.x >> 3;
    const int nblk  = gridDim.x >> 3;
    const int lo = (int)(((long)N * group) >> 3);
    const int hi = (int)(((long)N * (group + 1)) >> 3);
    const int nq = E >> 2;

    for (int i = gblk * 256 + threadIdx.x; i < nq; i += nblk * 256) {
        const int4 d = ((const int4*)dst)[i];
        const int4 s = ((const int4*)src)[i];
        if (d.x >= lo && d.x < hi) esrc[atomicAdd(&cursor[d.x], 1)] = s.x;
        if (d.y >= lo && d.y < hi) esrc[atomicAdd(&cursor[d.y], 1)] = s.y;
        if (d.z >= lo && d.z < hi) esrc[atomicAdd(&cursor[d.z], 1)] = s.z;
        if (d.w >= lo && d.w < hi) esrc[atomicAdd(&cursor[d.w], 1)] = s.w;
    }
    if (gblk == 0 && threadIdx.x == 0) {
        for (int e = nq * 4; e < E; ++e) {
            const int d = dst[e];
            if (d >= lo && d < hi) esrc[atomicAdd(&cursor[d], 1)] = src[e];
        }
    }
}

// ---------------- node-parallel segment max over bf16 rows ----------------
__global__ __launch_bounds__(256)
void agg_max_kernel(const int* __restrict__ row_ptr, const int* __restrict__ esrc,
                    const ushort* __restrict__ m, ushort* __restrict__ agg, int N)
{
    const int wid  = (int)(((size_t)blockIdx.x * 256 + threadIdx.x) >> 6);
    const int lane = threadIdx.x & 63;
    if (wid >= N) return;
    const int beg = row_ptr[wid];
    const int end = row_ptr[wid + 1];
    const size_t off = (size_t)(lane * 4);

    ushort4 a0 = make_ushort4(0, 0, 0, 0);
    ushort4 a1 = a0, a2 = a0, a3 = a0;
    int e = beg;
    for (; e + 8 <= end; e += 8) {
        int s[8];
#pragma unroll
        for (int q = 0; q < 8; ++q) s[q] = esrc[e + q];
        ushort4 v[8];
#pragma unroll
        for (int q = 0; q < 8; ++q)
            v[q] = *(const ushort4*)(m + (size_t)s[q] * D256 + off);
        a0 = vmax4(a0, vmax4(v[0], v[4]));
        a1 = vmax4(a1, vmax4(v[1], v[5]));
        a2 = vmax4(a2, vmax4(v[2], v[6]));
        a3 = vmax4(a3, vmax4(v[3], v[7]));
    }
    for (; e + 2 <= end; e += 2) {
        const int s0 = esrc[e];
        const int s1 = esrc[e + 1];
        const ushort4 v0 = *(const ushort4*)(m + (size_t)s0 * D256 + off);
        const ushort4 v1 = *(const ushort4*)(m + (size_t)s1 * D256 + off);
        a0 = vmax4(a0, v0);
        a1 = vmax4(a1, v1);
    }
    if (e < end) {
        const ushort4 v0 = *(const ushort4*)(m + (size_t)esrc[e] * D256 + off);
        a2 = vmax4(a2, v0);
    }
    const ushort4 r = vmax4(vmax4(a0, a1), vmax4(a2, a3));
    *(ushort4*)(agg + (size_t)wid * D256 + off) = r;
}

extern "C" void kernel_launch(void* const* d_in, const int* in_sizes, int n_in,
                              void* d_out, int out_size, void* d_ws, size_t ws_size,
                              hipStream_t stream)
{
    const float* x        = (const float*)d_in[0];
    const int*   src      = (const int*)  d_in[1];
    const int*   dst      = (const int*)  d_in[2];
    const float* W_pool0  = (const float*)d_in[3];
    const float* b_pool0  = (const float*)d_in[4];
    const float* W_self0  = (const float*)d_in[5];
    const float* W_neigh0 = (const float*)d_in[6];
    const float* b0       = (const float*)d_in[7];
    const float* W_pool1  = (const float*)d_in[8];
    const float* b_pool1  = (const float*)d_in[9];
    const float* W_self1  = (const float*)d_in[10];
    const float* W_neigh1 = (const float*)d_in[11];
    const float* b1       = (const float*)d_in[12];

    const int N = in_sizes[0] / D256;
    const int E = in_sizes[1];
    const size_t NR = (size_t)N * D256;

    float* h1  = (float*)d_out;                     // [N,256] layer-1 out (fp32)
    float* enc = (float*)d_out + NR;                // [N,256] enc_feat_input (fp32)

    ushort* xb   = (ushort*)d_ws;                   // bf16 A (x for L0, enc for L1)
    ushort* mb   = xb + NR;                         // bf16 pool msgs
    ushort* aggb = mb + NR;                         // bf16 aggregated
    float*  tmp  = (float*)(aggb + NR);             // (unused after fusion)
    ushort* Bt   = (ushort*)(tmp + NR);             // 6 x [256,256] bf16 W^T
    int* row_ptr = (int*)(Bt + 6 * 256 * 256);
    int* cursor  = row_ptr + (N + 1);
    int* deg     = cursor + N;
    int* incl    = deg + N;
    int* partials= incl + N;
    int* esrc    = partials + 1024;

    ushort* Bt_pool0  = Bt + 0 * 65536;
    ushort* Bt_self0  = Bt + 1 * 65536;
    ushort* Bt_neigh0 = Bt + 2 * 65536;
    ushort* Bt_pool1  = Bt + 3 * 65536;
    ushort* Bt_self1  = Bt + 4 * 65536;
    ushort* Bt_neigh1 = Bt + 5 * 65536;

    const int  gemm_blocks = ((N + 127) / 128) * 2;        // 1D swizzled grid
    const int  l2n_blocks  = (N + 63) / 64;                // fused full-row 64-row tile
    const int  q_blocks    = ((E >> 2) + 1 + 255) / 256;
    const int  bkt_blocks  = 2048;                         // 8 groups x 256
    const int  node_blocks = (N + 3) / 4;
    const int  conv_blocks = (int)((NR / 4 + 255) / 256);
    const int  scan_blocks = (N + 1023) / 1024;

    // ---------------- one-time conversions ----------------
    WP6 wp;
    wp.p[0] = { W_pool0,  Bt_pool0  };
    wp.p[1] = { W_self0,  Bt_self0  };
    wp.p[2] = { W_neigh0, Bt_neigh0 };
    wp.p[3] = { W_pool1,  Bt_pool1  };
    wp.p[4] = { W_self1,  Bt_self1  };
    wp.p[5] = { W_neigh1, Bt_neigh1 };
    wtrans_kernel<<<dim3(8, 8, 6), 256, 0, stream>>>(wp);
    f2bf_kernel<<<conv_blocks, 256, 0, stream>>>(x, xb, (int)(NR / 4));

    // ---------------- CSR build ----------------
    hipMemsetAsync(deg, 0, (size_t)N * sizeof(int), stream);
    hist_kernel<<<q_blocks, 256, 0, stream>>>(dst, deg, E);
    blockscan_kernel<<<scan_blocks, 1024, 0, stream>>>(deg, incl, partials, N);
    scanp_kernel<<<1, 1024, 0, stream>>>(partials, scan_blocks);
    finalize_kernel<<<scan_blocks, 1024, 0, stream>>>(deg, incl, partials,
                                                      row_ptr, cursor, N, E);
    bucket_kernel<<<bkt_blocks, 256, 0, stream>>>(src, dst, cursor, esrc, E, N);

    // ---------------- layer 0 ----------------
    mfma_gemm_kernel<0,1,1><<<gemm_blocks, 256, 0, stream>>>(xb, Bt_pool0, nullptr, nullptr,
                                                             b_pool0, mb, N);
    agg_max_kernel<<<node_blocks, 256, 0, stream>>>(row_ptr, esrc, mb, aggb, N);
    // fused: enc = l2norm(relu(x@Wself0 + agg@Wneigh0 + b0)); xb <- bf16(enc)
    mfma_dual_l2n_kernel<<<l2n_blocks, 256, 0, stream>>>(xb, Bt_self0, aggb, Bt_neigh0,
                                                         b0, enc, xb, N);

    // ---------------- layer 1 ----------------
    mfma_gemm_kernel<0,1,1><<<gemm_blocks, 256, 0, stream>>>(xb, Bt_pool1, nullptr, nullptr,
                                                             b_pool1, mb, N);
    agg_max_kernel<<<node_blocks, 256, 0, stream>>>(row_ptr, esrc, mb, aggb, N);
    mfma_gemm_kernel<1,0,0><<<gemm_blocks, 256, 0, stream>>>(xb, Bt_self1, aggb, Bt_neigh1,
                                                             b1, h1, N);
}

// Round 17
// 333.550 us; speedup vs baseline: 1.2368x; 1.0267x over previous
//
#include <hip/hip_runtime.h>
#include <cstddef>

#define D256 256

typedef __attribute__((ext_vector_type(8))) short bf16x8;
typedef __attribute__((ext_vector_type(4))) float f32x4;

// global -> LDS direct (16B per lane, wave-uniform LDS base + lane*16)
#define GLOAD16(gptr, lptr)                                                         \
    __builtin_amdgcn_global_load_lds(                                               \
        (const __attribute__((address_space(1))) unsigned int*)(gptr),              \
        (__attribute__((address_space(3))) unsigned int*)(lptr), 16, 0, 0)

__device__ __forceinline__ ushort f2bf(float f) {
    unsigned u = __float_as_uint(f);
    return (ushort)((u + 0x7FFFu + ((u >> 16) & 1u)) >> 16);   // RNE
}
__device__ __forceinline__ ushort umax16(ushort a, ushort b) { return a > b ? a : b; }
__device__ __forceinline__ ushort4 vmax4(ushort4 a, ushort4 b) {
    return make_ushort4(umax16(a.x, b.x), umax16(a.y, b.y),
                        umax16(a.z, b.z), umax16(a.w, b.w));
}

// ---------------- MFMA GEMM: out = act( A@Bt^T (+ A2@Bt2^T) + bias ) ----------------
// 128x128 tile, 4 waves (2x2), 64x64/wave, BK=32, 16x16x32 MFMA.
// 2-phase dbuf global_load_lds staging; 1D grid + bijective XCD swizzle (m204).
// Swapped-operand mfma(bf, af): D frag = (m = lane&15, n = kg*4 + reg).
template<int DUAL, int RELU, int OUT_BF16>
__global__ __launch_bounds__(256)
void mfma_gemm_kernel(const ushort* __restrict__ A, const ushort* __restrict__ Bt,
                      const ushort* __restrict__ A2, const ushort* __restrict__ Bt2,
                      const float* __restrict__ bias, void* __restrict__ outp, int M)
{
    constexpr int TILES = DUAL ? 4 : 2;          // A,B[,A2,B2]
    constexpr int BUFSZ = TILES * 4096;          // ushorts per buffer
    __shared__ ushort smem[2 * BUFSZ];

    // bijective XCD swizzle (nwg need not be a multiple of 8)
    const int nwg  = gridDim.x;
    const int q    = nwg >> 3, r = nwg & 7;
    const int xcd  = blockIdx.x & 7, jj = blockIdx.x >> 3;
    const int wgid = (xcd < r ? xcd * (q + 1) : r * (q + 1) + (xcd - r) * q) + jj;

    const int t    = threadIdx.x;
    const int m0   = (wgid >> 1) * 128;
    const int n0   = (wgid & 1) * 128;
    const int lane = t & 63;
    const int wave = t >> 6;
    const int wr   = (wave >> 1) * 64;
    const int wc   = (wave & 1) * 64;
    const int lr   = lane & 15;
    const int kg   = lane >> 4;

    const int lrow  = lane >> 2;
    const int lch   = lane & 3;
    const int srow0 = wave * 32;

    f32x4 acc[4][4];
#pragma unroll
    for (int i = 0; i < 4; ++i)
#pragma unroll
        for (int j = 0; j < 4; ++j) acc[i][j] = (f32x4)(0.0f);

    auto STAGE = [&](int buf, int k0) {
        ushort* const base = smem + buf * BUFSZ;
#pragma unroll
        for (int i = 0; i < 2; ++i) {
            const int r2  = srow0 + i * 16;
            const int ar  = m0 + r2 + lrow;
            const int arc = ar < M ? ar : (M - 1);
            const size_t ga = (size_t)arc * D256 + k0 + lch * 8;
            const size_t gb = (size_t)(n0 + r2 + lrow) * D256 + k0 + lch * 8;
            GLOAD16(A + ga, base + r2 * 32);
            GLOAD16(Bt + gb, base + 4096 + r2 * 32);
            if (DUAL) {
                GLOAD16(A2 + ga, base + 8192 + r2 * 32);
                GLOAD16(Bt2 + gb, base + 12288 + r2 * 32);
            }
        }
    };

    STAGE(0, 0);
#pragma unroll
    for (int ks = 0; ks < 8; ++ks) {
        const int cur = ks & 1;
        __syncthreads();
        if (ks < 7) STAGE(cur ^ 1, (ks + 1) * 32);

        ushort* const base = smem + cur * BUFSZ;
        bf16x8 af[4], bf[4];
#pragma unroll
        for (int mi = 0; mi < 4; ++mi)
            af[mi] = *(const bf16x8*)&base[(wr + mi * 16 + lr) * 32 + kg * 8];
#pragma unroll
        for (int ni = 0; ni < 4; ++ni)
            bf[ni] = *(const bf16x8*)&base[4096 + (wc + ni * 16 + lr) * 32 + kg * 8];
#pragma unroll
        for (int mi = 0; mi < 4; ++mi)
#pragma unroll
            for (int ni = 0; ni < 4; ++ni)
                acc[mi][ni] = __builtin_amdgcn_mfma_f32_16x16x32_bf16(
                    bf[ni], af[mi], acc[mi][ni], 0, 0, 0);
        if (DUAL) {
            bf16x8 af2[4], bf2[4];
#pragma unroll
            for (int mi = 0; mi < 4; ++mi)
                af2[mi] = *(const bf16x8*)&base[8192 + (wr + mi * 16 + lr) * 32 + kg * 8];
#pragma unroll
            for (int ni = 0; ni < 4; ++ni)
                bf2[ni] = *(const bf16x8*)&base[12288 + (wc + ni * 16 + lr) * 32 + kg * 8];
#pragma unroll
            for (int mi = 0; mi < 4; ++mi)
#pragma unroll
                for (int ni = 0; ni < 4; ++ni)
                    acc[mi][ni] = __builtin_amdgcn_mfma_f32_16x16x32_bf16(
                        bf2[ni], af2[mi], acc[mi][ni], 0, 0, 0);
        }
    }

#pragma unroll
    for (int ni = 0; ni < 4; ++ni) {
        const int colb = n0 + wc + ni * 16 + kg * 4;
        const float4 bb = *(const float4*)(bias + colb);
#pragma unroll
        for (int mi = 0; mi < 4; ++mi) {
            const int row = m0 + wr + mi * 16 + lr;
            if (row < M) {
                const f32x4 a = acc[mi][ni];
                float4 o;
                o.x = a[0] + bb.x;
                o.y = a[1] + bb.y;
                o.z = a[2] + bb.z;
                o.w = a[3] + bb.w;
                if (RELU) {
                    o.x = fmaxf(o.x, 0.f); o.y = fmaxf(o.y, 0.f);
                    o.z = fmaxf(o.z, 0.f); o.w = fmaxf(o.w, 0.f);
                }
                if (OUT_BF16) {
                    ushort4 ob;
                    ob.x = f2bf(o.x); ob.y = f2bf(o.y);
                    ob.z = f2bf(o.z); ob.w = f2bf(o.w);
                    *(ushort4*)((ushort*)outp + (size_t)row * D256 + colb) = ob;
                } else {
                    *(float4*)((float*)outp + (size_t)row * D256 + colb) = o;
                }
            }
        }
    }
}

// ------ fused dual GEMM + relu + row-l2norm: enc_f = l2n(relu(A@Bt^T + A2@Bt2^T + b)),
// ------ enc_b = bf16(enc_f). Tile 64 rows x FULL 256 cols (block owns whole rows).
__global__ __launch_bounds__(256)
void mfma_dual_l2n_kernel(const ushort* A, const ushort* __restrict__ Bt,
                          const ushort* __restrict__ A2, const ushort* __restrict__ Bt2,
                          const float* __restrict__ bias,
                          float* __restrict__ enc_f, ushort* enc_b, int M)
{
    __shared__ ushort smem[20480];        // A:0 | A2:2048 | B:4096 | B2:12288
    __shared__ float  ssq_lds[64][2];

    const int t    = threadIdx.x;
    const int m0   = blockIdx.x * 64;
    const int lane = t & 63;
    const int wave = t >> 6;
    const int wr   = (wave >> 1) * 32;    // rows 0-31 / 32-63
    const int wc   = (wave & 1) * 128;    // cols 0-127 / 128-255
    const int lr   = lane & 15;
    const int kg   = lane >> 4;
    const int lrow = lane >> 2;
    const int lch  = lane & 3;

    f32x4 acc[2][8];
#pragma unroll
    for (int i = 0; i < 2; ++i)
#pragma unroll
        for (int j = 0; j < 8; ++j) acc[i][j] = (f32x4)(0.0f);

    for (int ks = 0; ks < 8; ++ks) {
        const int k0 = ks * 32;
        __syncthreads();
        {
            const int r2  = wave * 16;
            const int ar  = m0 + r2 + lrow;
            const int arc = ar < M ? ar : (M - 1);
            const size_t ga = (size_t)arc * D256 + k0 + lch * 8;
            GLOAD16(A + ga, smem + r2 * 32);
            GLOAD16(A2 + ga, smem + 2048 + r2 * 32);
        }
#pragma unroll
        for (int i = 0; i < 4; ++i) {
            const int r2 = wave * 64 + i * 16;
            const size_t gb = (size_t)(r2 + lrow) * D256 + k0 + lch * 8;
            GLOAD16(Bt + gb, smem + 4096 + r2 * 32);
            GLOAD16(Bt2 + gb, smem + 12288 + r2 * 32);
        }
        __syncthreads();

        bf16x8 af[2];
#pragma unroll
        for (int mi = 0; mi < 2; ++mi)
            af[mi] = *(const bf16x8*)&smem[(wr + mi * 16 + lr) * 32 + kg * 8];
#pragma unroll
        for (int ni = 0; ni < 8; ++ni) {
            const bf16x8 b = *(const bf16x8*)&smem[4096 + (wc + ni * 16 + lr) * 32 + kg * 8];
#pragma unroll
            for (int mi = 0; mi < 2; ++mi)
                acc[mi][ni] = __builtin_amdgcn_mfma_f32_16x16x32_bf16(
                    b, af[mi], acc[mi][ni], 0, 0, 0);
        }
#pragma unroll
        for (int mi = 0; mi < 2; ++mi)
            af[mi] = *(const bf16x8*)&smem[2048 + (wr + mi * 16 + lr) * 32 + kg * 8];
#pragma unroll
        for (int ni = 0; ni < 8; ++ni) {
            const bf16x8 b = *(const bf16x8*)&smem[12288 + (wc + ni * 16 + lr) * 32 + kg * 8];
#pragma unroll
            for (int mi = 0; mi < 2; ++mi)
                acc[mi][ni] = __builtin_amdgcn_mfma_f32_16x16x32_bf16(
                    b, af[mi], acc[mi][ni], 0, 0, 0);
        }
    }

    float ssq[2] = {0.f, 0.f};
#pragma unroll
    for (int mi = 0; mi < 2; ++mi)
#pragma unroll
        for (int ni = 0; ni < 8; ++ni) {
            const int colb = wc + ni * 16 + kg * 4;
            const float4 bb = *(const float4*)(bias + colb);
            f32x4 a = acc[mi][ni];
            a[0] = fmaxf(a[0] + bb.x, 0.f);
            a[1] = fmaxf(a[1] + bb.y, 0.f);
            a[2] = fmaxf(a[2] + bb.z, 0.f);
            a[3] = fmaxf(a[3] + bb.w, 0.f);
            acc[mi][ni] = a;
            ssq[mi] += a[0] * a[0] + a[1] * a[1] + a[2] * a[2] + a[3] * a[3];
        }
#pragma unroll
    for (int mi = 0; mi < 2; ++mi) {
        ssq[mi] += __shfl_xor(ssq[mi], 16);
        ssq[mi] += __shfl_xor(ssq[mi], 32);
    }
    __syncthreads();
    if (kg == 0) {
#pragma unroll
        for (int mi = 0; mi < 2; ++mi)
            ssq_lds[wr + mi * 16 + lr][wave & 1] = ssq[mi];
    }
    __syncthreads();
#pragma unroll
    for (int mi = 0; mi < 2; ++mi) {
        const int rrow = wr + mi * 16 + lr;
        const int row  = m0 + rrow;
        const float tot = ssq_lds[rrow][0] + ssq_lds[rrow][1];
        const float inv = 1.0f / fmaxf(sqrtf(tot), 1e-12f);
        if (row < M) {
#pragma unroll
            for (int ni = 0; ni < 8; ++ni) {
                const int colb = wc + ni * 16 + kg * 4;
                const f32x4 a = acc[mi][ni];
                float4 o;
                o.x = a[0] * inv; o.y = a[1] * inv;
                o.z = a[2] * inv; o.w = a[3] * inv;
                *(float4*)(enc_f + (size_t)row * D256 + colb) = o;
                ushort4 ob;
                ob.x = f2bf(o.x); ob.y = f2bf(o.y);
                ob.z = f2bf(o.z); ob.w = f2bf(o.w);
                *(ushort4*)(enc_b + (size_t)row * D256 + colb) = ob;
            }
        }
    }
}

// ---------------- merged prep: 6x weight transpose+convert | x->bf16 | deg zero ----------------
// blocks [0,384): wtrans tile (wb = blk/64, tile = blk%64 -> 8x8 k/n tiles)
// blocks [384, 384+nconv): f2bf chunk
// blocks [384+nconv, ...): zero deg
struct WP  { const float* w; ushort* o; };
struct WP6 { WP p[6]; };
__global__ __launch_bounds__(256)
void prep_kernel(WP6 ps, const float* __restrict__ xin, ushort* __restrict__ xout,
                 int n4, int* __restrict__ deg, int N, int nconv)
{
    const int b = blockIdx.x;
    if (b < 384) {                        // weight transpose: 6 x (8x8 32x32-tiles)
        const int wb   = b >> 6;
        const int tile = b & 63;
        const float* __restrict__ W = ps.p[wb].w;
        ushort* __restrict__ O      = ps.p[wb].o;
        __shared__ float sm[32][33];
        const int tx = threadIdx.x & 31, ty = threadIdx.x >> 5;
        const int k0 = (tile >> 3) * 32, n0 = (tile & 7) * 32;
#pragma unroll
        for (int i = 0; i < 4; ++i)
            sm[ty + i * 8][tx] = W[(size_t)(k0 + ty + i * 8) * D256 + n0 + tx];
        __syncthreads();
#pragma unroll
        for (int i = 0; i < 4; ++i)
            O[(size_t)(n0 + ty + i * 8) * D256 + k0 + tx] = f2bf(sm[tx][ty + i * 8]);
    } else if (b < 384 + nconv) {         // x -> bf16
        const int i = (b - 384) * 256 + threadIdx.x;
        if (i < n4) {
            const float4 v = ((const float4*)xin)[i];
            ushort4 o;
            o.x = f2bf(v.x); o.y = f2bf(v.y); o.z = f2bf(v.z); o.w = f2bf(v.w);
            ((ushort4*)xout)[i] = o;
        }
    } else {                              // zero deg
        const int i = (b - 384 - nconv) * 256 + threadIdx.x;
        if (i < N) deg[i] = 0;
    }
}

// ---------------- CSR build ----------------
__global__ __launch_bounds__(256)
void hist_kernel(const int* __restrict__ dst, int* __restrict__ deg, int E)
{
    const int nq = E >> 2;
    const int i  = blockIdx.x * 256 + threadIdx.x;
    if (i < nq) {
        const int4 d = ((const int4*)dst)[i];
        atomicAdd(&deg[d.x], 1);
        atomicAdd(&deg[d.y], 1);
        atomicAdd(&deg[d.z], 1);
        atomicAdd(&deg[d.w], 1);
    } else if (i == nq) {
        for (int e = nq * 4; e < E; ++e) atomicAdd(&deg[dst[e]], 1);
    }
}

__global__ __launch_bounds__(1024)
void blockscan_kernel(const int* __restrict__ deg, int* __restrict__ incl,
                      int* __restrict__ partials, int N)
{
    __shared__ int wt[16];
    const int i    = blockIdx.x * 1024 + threadIdx.x;
    const int lane = threadIdx.x & 63;
    const int wv   = threadIdx.x >> 6;
    const int v    = (i < N) ? deg[i] : 0;
    int s = v;
#pragma unroll
    for (int o = 1; o < 64; o <<= 1) {
        const int t = __shfl_up(s, o);
        if (lane >= o) s += t;
    }
    if (lane == 63) wt[wv] = s;
    __syncthreads();
    if (wv == 0 && lane < 16) {
        const int w = wt[lane];
        int ws = w;
#pragma unroll
        for (int o = 1; o < 16; o <<= 1) {
            const int t = __shfl_up(ws, o);
            if (lane >= o) ws += t;
        }
        wt[lane] = ws - w;
    }
    __syncthreads();
    s += wt[wv];
    if (i < N) incl[i] = s;
    if (threadIdx.x == 1023) partials[blockIdx.x] = s;
}

__global__ __launch_bounds__(1024)
void scanp_kernel(int* __restrict__ partials, int nb)
{
    __shared__ int sm[1024];
    const int v = (threadIdx.x < (unsigned)nb) ? partials[threadIdx.x] : 0;
    sm[threadIdx.x] = v;
    __syncthreads();
#pragma unroll
    for (int off = 1; off < 1024; off <<= 1) {
        const int t = (threadIdx.x >= (unsigned)off) ? sm[threadIdx.x - off] : 0;
        __syncthreads();
        sm[threadIdx.x] += t;
        __syncthreads();
    }
    if (threadIdx.x < (unsigned)nb) partials[threadIdx.x] = sm[threadIdx.x] - v;
}

__global__ __launch_bounds__(1024)
void finalize_kernel(const int* __restrict__ deg, const int* __restrict__ incl,
                     const int* __restrict__ partials, int* __restrict__ row_ptr,
                     int* __restrict__ cursor, int N, int E)
{
    const int i = blockIdx.x * 1024 + threadIdx.x;
    if (i < N) {
        const int ex = partials[blockIdx.x] + incl[i] - deg[i];
        row_ptr[i] = ex;
        cursor[i]  = ex;
    }
    if (i == 0) row_ptr[N] = E;
}

// dst-range-partitioned bucket scatter (one XCD owns each esrc range)
__global__ __launch_bounds__(256)
void bucket_kernel(const int* __restrict__ src, const int* __restrict__ dst,
                   int* __restrict__ cursor, int* __restrict__ esrc, int E, int N)
{
    const int group = blockIdx.x & 7;
    const int gblk  = blockIdx.x >> 3;
    const int nblk  = gridDim.x >> 3;
    const int lo = (int)(((long)N * group) >> 3);
    const int hi = (int)(((long)N * (group + 1)) >> 3);
    const int nq = E >> 2;

    for (int i = gblk * 256 + threadIdx.x; i < nq; i += nblk * 256) {
        const int4 d = ((const int4*)dst)[i];
        const int4 s = ((const int4*)src)[i];
        if (d.x >= lo && d.x < hi) esrc[atomicAdd(&cursor[d.x], 1)] = s.x;
        if (d.y >= lo && d.y < hi) esrc[atomicAdd(&cursor[d.y], 1)] = s.y;
        if (d.z >= lo && d.z < hi) esrc[atomicAdd(&cursor[d.z], 1)] = s.z;
        if (d.w >= lo && d.w < hi) esrc[atomicAdd(&cursor[d.w], 1)] = s.w;
    }
    if (gblk == 0 && threadIdx.x == 0) {
        for (int e = nq * 4; e < E; ++e) {
            const int d = dst[e];
            if (d >= lo && d < hi) esrc[atomicAdd(&cursor[d], 1)] = src[e];
        }
    }
}

// ---------------- node-parallel segment max over bf16 rows ----------------
__global__ __launch_bounds__(256)
void agg_max_kernel(const int* __restrict__ row_ptr, const int* __restrict__ esrc,
                    const ushort* __restrict__ m, ushort* __restrict__ agg, int N)
{
    const int wid  = (int)(((size_t)blockIdx.x * 256 + threadIdx.x) >> 6);
    const int lane = threadIdx.x & 63;
    if (wid >= N) return;
    const int beg = row_ptr[wid];
    const int end = row_ptr[wid + 1];
    const size_t off = (size_t)(lane * 4);

    ushort4 a0 = make_ushort4(0, 0, 0, 0);
    ushort4 a1 = a0, a2 = a0, a3 = a0;
    int e = beg;
    for (; e + 8 <= end; e += 8) {
        int s[8];
#pragma unroll
        for (int q = 0; q < 8; ++q) s[q] = esrc[e + q];
        ushort4 v[8];
#pragma unroll
        for (int q = 0; q < 8; ++q)
            v[q] = *(const ushort4*)(m + (size_t)s[q] * D256 + off);
        a0 = vmax4(a0, vmax4(v[0], v[4]));
        a1 = vmax4(a1, vmax4(v[1], v[5]));
        a2 = vmax4(a2, vmax4(v[2], v[6]));
        a3 = vmax4(a3, vmax4(v[3], v[7]));
    }
    for (; e + 2 <= end; e += 2) {
        const int s0 = esrc[e];
        const int s1 = esrc[e + 1];
        const ushort4 v0 = *(const ushort4*)(m + (size_t)s0 * D256 + off);
        const ushort4 v1 = *(const ushort4*)(m + (size_t)s1 * D256 + off);
        a0 = vmax4(a0, v0);
        a1 = vmax4(a1, v1);
    }
    if (e < end) {
        const ushort4 v0 = *(const ushort4*)(m + (size_t)esrc[e] * D256 + off);
        a2 = vmax4(a2, v0);
    }
    const ushort4 r = vmax4(vmax4(a0, a1), vmax4(a2, a3));
    *(ushort4*)(agg + (size_t)wid * D256 + off) = r;
}

extern "C" void kernel_launch(void* const* d_in, const int* in_sizes, int n_in,
                              void* d_out, int out_size, void* d_ws, size_t ws_size,
                              hipStream_t stream)
{
    const float* x        = (const float*)d_in[0];
    const int*   src      = (const int*)  d_in[1];
    const int*   dst      = (const int*)  d_in[2];
    const float* W_pool0  = (const float*)d_in[3];
    const float* b_pool0  = (const float*)d_in[4];
    const float* W_self0  = (const float*)d_in[5];
    const float* W_neigh0 = (const float*)d_in[6];
    const float* b0       = (const float*)d_in[7];
    const float* W_pool1  = (const float*)d_in[8];
    const float* b_pool1  = (const float*)d_in[9];
    const float* W_self1  = (const float*)d_in[10];
    const float* W_neigh1 = (const float*)d_in[11];
    const float* b1       = (const float*)d_in[12];

    const int N = in_sizes[0] / D256;
    const int E = in_sizes[1];
    const size_t NR = (size_t)N * D256;

    float* h1  = (float*)d_out;                     // [N,256] layer-1 out (fp32)
    float* enc = (float*)d_out + NR;                // [N,256] enc_feat_input (fp32)

    ushort* xb   = (ushort*)d_ws;                   // bf16 A (x for L0, enc for L1)
    ushort* mb   = xb + NR;                         // bf16 pool msgs
    ushort* aggb = mb + NR;                         // bf16 aggregated
    float*  tmp  = (float*)(aggb + NR);             // (unused after fusion)
    ushort* Bt   = (ushort*)(tmp + NR);             // 6 x [256,256] bf16 W^T
    int* row_ptr = (int*)(Bt + 6 * 256 * 256);
    int* cursor  = row_ptr + (N + 1);
    int* deg     = cursor + N;
    int* incl    = deg + N;
    int* partials= incl + N;
    int* esrc    = partials + 1024;

    ushort* Bt_pool0  = Bt + 0 * 65536;
    ushort* Bt_self0  = Bt + 1 * 65536;
    ushort* Bt_neigh0 = Bt + 2 * 65536;
    ushort* Bt_pool1  = Bt + 3 * 65536;
    ushort* Bt_self1  = Bt + 4 * 65536;
    ushort* Bt_neigh1 = Bt + 5 * 65536;

    const int  gemm_blocks = ((N + 127) / 128) * 2;        // 1D swizzled grid
    const int  l2n_blocks  = (N + 63) / 64;                // fused full-row 64-row tile
    const int  q_blocks    = ((E >> 2) + 1 + 255) / 256;
    const int  bkt_blocks  = 2048;                         // 8 groups x 256
    const int  node_blocks = (N + 3) / 4;
    const int  n4          = (int)(NR / 4);
    const int  conv_blocks = (n4 + 255) / 256;
    const int  degz_blocks = (N + 255) / 256;
    const int  prep_blocks = 384 + conv_blocks + degz_blocks;
    const int  scan_blocks = (N + 1023) / 1024;

    // ---------------- merged prep: weight transpose + x->bf16 + deg zero ----------------
    WP6 wp;
    wp.p[0] = { W_pool0,  Bt_pool0  };
    wp.p[1] = { W_self0,  Bt_self0  };
    wp.p[2] = { W_neigh0, Bt_neigh0 };
    wp.p[3] = { W_pool1,  Bt_pool1  };
    wp.p[4] = { W_self1,  Bt_self1  };
    wp.p[5] = { W_neigh1, Bt_neigh1 };
    prep_kernel<<<prep_blocks, 256, 0, stream>>>(wp, x, xb, n4, deg, N, conv_blocks);

    // ---------------- CSR build ----------------
    hist_kernel<<<q_blocks, 256, 0, stream>>>(dst, deg, E);
    blockscan_kernel<<<scan_blocks, 1024, 0, stream>>>(deg, incl, partials, N);
    scanp_kernel<<<1, 1024, 0, stream>>>(partials, scan_blocks);
    finalize_kernel<<<scan_blocks, 1024, 0, stream>>>(deg, incl, partials,
                                                      row_ptr, cursor, N, E);
    bucket_kernel<<<bkt_blocks, 256, 0, stream>>>(src, dst, cursor, esrc, E, N);

    // ---------------- layer 0 ----------------
    mfma_gemm_kernel<0,1,1><<<gemm_blocks, 256, 0, stream>>>(xb, Bt_pool0, nullptr, nullptr,
                                                             b_pool0, mb, N);
    agg_max_kernel<<<node_blocks, 256, 0, stream>>>(row_ptr, esrc, mb, aggb, N);
    // fused: enc = l2norm(relu(x@Wself0 + agg@Wneigh0 + b0)); xb <- bf16(enc)
    mfma_dual_l2n_kernel<<<l2n_blocks, 256, 0, stream>>>(xb, Bt_self0, aggb, Bt_neigh0,
                                                         b0, enc, xb, N);

    // ---------------- layer 1 ----------------
    mfma_gemm_kernel<0,1,1><<<gemm_blocks, 256, 0, stream>>>(xb, Bt_pool1, nullptr, nullptr,
                                                             b_pool1, mb, N);
    agg_max_kernel<<<node_blocks, 256, 0, stream>>>(row_ptr, esrc, mb, aggb, N);
    mfma_gemm_kernel<1,0,0><<<gemm_blocks, 256, 0, stream>>>(xb, Bt_self1, aggb, Bt_neigh1,
                                                             b1, h1, N);
}